// Round 1
// 141.973 us; speedup vs baseline: 1.0706x; 1.0706x over previous
//
#include <hip/hip_runtime.h>
#include <math.h>

#define PI_F 3.14159265358979323846f

// ---------- complex helpers (float2 as complex) ----------
__device__ __forceinline__ float2 cmul2(float2 a, float2 b) {
    return make_float2(a.x * b.x - a.y * b.y, a.x * b.y + a.y * b.x);
}
// u*a + v*b
__device__ __forceinline__ float2 cmac2(float2 u, float2 a, float2 v, float2 b) {
    float2 r;
    r.x = u.x * a.x - u.y * a.y + v.x * b.x - v.y * b.y;
    r.y = u.x * a.y + u.y * a.x + v.x * b.y + v.y * b.x;
    return r;
}

struct M4 { float2 u00, u01, u10, u11; };

__device__ __forceinline__ M4 mmul4(const M4& A, const M4& B) {
    M4 R;
    R.u00 = cmac2(A.u00, B.u00, A.u01, B.u10);
    R.u01 = cmac2(A.u00, B.u01, A.u01, B.u11);
    R.u10 = cmac2(A.u10, B.u00, A.u11, B.u10);
    R.u11 = cmac2(A.u10, B.u01, A.u11, B.u11);
    return R;
}
__device__ __forceinline__ M4 mry(float t) {
    float c = cosf(0.5f * t), s = sinf(0.5f * t);
    M4 R; R.u00 = {c, 0}; R.u01 = {-s, 0}; R.u10 = {s, 0}; R.u11 = {c, 0};
    return R;
}
__device__ __forceinline__ M4 mrz(float t) {
    float c = cosf(0.5f * t), s = sinf(0.5f * t);
    M4 R; R.u00 = {c, -s}; R.u01 = {0, 0}; R.u10 = {0, 0}; R.u11 = {c, s};
    return R;
}
// Rot(phi, theta, omega) = RZ(omega) @ RY(theta) @ RZ(phi)
__device__ __forceinline__ M4 mrot(float phi, float th, float om) {
    return mmul4(mmul4(mrz(om), mry(th)), mrz(phi));
}

__device__ __forceinline__ float2 shflx(float2 v, int mask) {
    return make_float2(__shfl_xor(v.x, mask, 64), __shfl_xor(v.y, mask, 64));
}

// load an M4 from wave-uniform global memory (compiler emits scalar loads)
__device__ __forceinline__ M4 ldm(const float* __restrict__ g) {
    M4 M;
    M.u00 = make_float2(g[0], g[1]); M.u01 = make_float2(g[2], g[3]);
    M.u10 = make_float2(g[4], g[5]); M.u11 = make_float2(g[6], g[7]);
    return M;
}

// ---------- register statevector: idx = lane*8 + r ----------
// idx bit b: b in [0,2] -> register bit b; b in [3,8] -> lane bit (b-3).
// wire w -> idx bit (8-w). Wires 0..5 = lane bits 5..0; wires 6,7,8 = reg bits 2,1,0.

// single-qubit dense gate on register bit TB
template <int TB>
__device__ __forceinline__ void rot_reg(const M4& U, float2 (&amp)[8]) {
#pragma unroll
    for (int r = 0; r < 8; r++)
        if (((r >> TB) & 1) == 0) {
            int r1 = r | (1 << TB);
            float2 a = amp[r], b = amp[r1];
            amp[r]  = cmac2(U.u00, a, U.u01, b);
            amp[r1] = cmac2(U.u10, a, U.u11, b);
        }
}

// single-qubit dense gate on lane bit LB
template <int LB>
__device__ __forceinline__ void rot_lane(const M4& U, float2 (&amp)[8], int lane) {
    bool hi = (lane >> LB) & 1;
    float2 cA = hi ? U.u11 : U.u00;
    float2 cB = hi ? U.u10 : U.u01;
#pragma unroll
    for (int r = 0; r < 8; r++) {
        float2 o = shflx(amp[r], 1 << LB);
        amp[r] = cmac2(cA, amp[r], cB, o);
    }
}

template <int WIRE>
__device__ __forceinline__ void rot1(const M4& U, float2 (&amp)[8], int lane) {
    constexpr int BIT = 8 - WIRE;
    if constexpr (BIT < 3) rot_reg<BIT>(U, amp);
    else rot_lane<BIT - 3>(U, amp, lane);
}

// ---------- specialized controlled rotations (target = reg bit TB) ----------

// controlled RX: [[c, -i s], [-i s, c]]
template <int CBIT, int TB>
__device__ __forceinline__ void crx_g(float c, float s, float2 (&amp)[8], int lane) {
    if constexpr (CBIT >= 3) {
        bool ct = (lane >> (CBIT - 3)) & 1;
        float cc = ct ? c : 1.f, ss = ct ? s : 0.f;
#pragma unroll
        for (int r = 0; r < 8; r++)
            if (((r >> TB) & 1) == 0) {
                int r1 = r | (1 << TB);
                float2 a = amp[r], b = amp[r1];
                amp[r]  = make_float2(cc * a.x + ss * b.y, cc * a.y - ss * b.x);
                amp[r1] = make_float2(ss * a.y + cc * b.x, cc * b.y - ss * a.x);
            }
    } else {
#pragma unroll
        for (int r = 0; r < 8; r++)
            if (((r >> CBIT) & 1) == 1 && ((r >> TB) & 1) == 0) {
                int r1 = r | (1 << TB);
                float2 a = amp[r], b = amp[r1];
                amp[r]  = make_float2(c * a.x + s * b.y, c * a.y - s * b.x);
                amp[r1] = make_float2(s * a.y + c * b.x, c * b.y - s * a.x);
            }
    }
}

// controlled RY: [[c, -s], [s, c]] (real)
template <int CBIT, int TB>
__device__ __forceinline__ void cry_g(float c, float s, float2 (&amp)[8], int lane) {
    if constexpr (CBIT >= 3) {
        bool ct = (lane >> (CBIT - 3)) & 1;
        float cc = ct ? c : 1.f, ss = ct ? s : 0.f;
#pragma unroll
        for (int r = 0; r < 8; r++)
            if (((r >> TB) & 1) == 0) {
                int r1 = r | (1 << TB);
                float2 a = amp[r], b = amp[r1];
                amp[r]  = make_float2(cc * a.x - ss * b.x, cc * a.y - ss * b.y);
                amp[r1] = make_float2(ss * a.x + cc * b.x, ss * a.y + cc * b.y);
            }
    } else {
#pragma unroll
        for (int r = 0; r < 8; r++)
            if (((r >> CBIT) & 1) == 1 && ((r >> TB) & 1) == 0) {
                int r1 = r | (1 << TB);
                float2 a = amp[r], b = amp[r1];
                amp[r]  = make_float2(c * a.x - s * b.x, c * a.y - s * b.y);
                amp[r1] = make_float2(s * a.x + c * b.x, s * a.y + c * b.y);
            }
    }
}

// controlled RZ: diag(e, conj(e)), e = c - i s
template <int CBIT, int TB>
__device__ __forceinline__ void crz_g(float c, float s, float2 (&amp)[8], int lane) {
    if constexpr (CBIT >= 3) {
        bool ct = (lane >> (CBIT - 3)) & 1;
        float cc = ct ? c : 1.f, ss = ct ? s : 0.f;
#pragma unroll
        for (int r = 0; r < 8; r++)
            if (((r >> TB) & 1) == 0) {
                int r1 = r | (1 << TB);
                float2 a = amp[r], b = amp[r1];
                amp[r]  = make_float2(cc * a.x + ss * a.y, cc * a.y - ss * a.x);
                amp[r1] = make_float2(cc * b.x - ss * b.y, cc * b.y + ss * b.x);
            }
    } else {
#pragma unroll
        for (int r = 0; r < 8; r++)
            if (((r >> CBIT) & 1) == 1 && ((r >> TB) & 1) == 0) {
                int r1 = r | (1 << TB);
                float2 a = amp[r], b = amp[r1];
                amp[r]  = make_float2(c * a.x + s * a.y, c * a.y - s * a.x);
                amp[r1] = make_float2(c * b.x - s * b.y, c * b.y + s * b.x);
            }
    }
}

template <int CW, int TW>
__device__ __forceinline__ void cnotg(float2 (&amp)[8], int lane) {
    constexpr int CBIT = 8 - CW, TBIT = 8 - TW;
    if constexpr (CBIT < 3 && TBIT < 3) {
#pragma unroll
        for (int r = 0; r < 8; r++)
            if (((r >> CBIT) & 1) == 1 && ((r >> TBIT) & 1) == 0) {
                int r1 = r | (1 << TBIT);
                float2 t = amp[r]; amp[r] = amp[r1]; amp[r1] = t;
            }
    } else if constexpr (CBIT >= 3 && TBIT < 3) {
        bool c = (lane >> (CBIT - 3)) & 1;
#pragma unroll
        for (int r = 0; r < 8; r++)
            if (((r >> TBIT) & 1) == 0) {
                int r1 = r | (1 << TBIT);
                float2 t0 = amp[r], t1 = amp[r1];
                amp[r]  = c ? t1 : t0;
                amp[r1] = c ? t0 : t1;
            }
    } else if constexpr (CBIT < 3 && TBIT >= 3) {
#pragma unroll
        for (int r = 0; r < 8; r++)
            if (((r >> CBIT) & 1) == 1) {
                amp[r] = shflx(amp[r], 1 << (TBIT - 3));
            }
    } else {
        bool c = (lane >> (CBIT - 3)) & 1;
#pragma unroll
        for (int r = 0; r < 8; r++) {
            float2 o = shflx(amp[r], 1 << (TBIT - 3));
            amp[r] = c ? o : amp[r];
        }
    }
}

// StronglyEntanglingLayers, L=1, 3 wires; gm = 3 precomputed dense Rot matrices
template <int W0, int W1, int W2>
__device__ __forceinline__ void sel3m(const float* __restrict__ gm, float2 (&amp)[8], int lane) {
    rot1<W0>(ldm(gm),      amp, lane);
    rot1<W1>(ldm(gm + 8),  amp, lane);
    rot1<W2>(ldm(gm + 16), amp, lane);
    cnotg<W0, W1>(amp, lane);
    cnotg<W1, W2>(amp, lane);
    cnotg<W2, W0>(amp, lane);
}

// gm layout (floats): [0..7] (c,s) x4 ctrl gates; [8..31] strong[0]; [32..55] strong[1]; [56..79] update
template <int I>
__device__ __forceinline__ void block_i(float2 (&amp)[8], float cx, float sx, float cy1, float sy1,
                                        float cz, float sz, float cy2, float sy2,
                                        const float* __restrict__ gm, int lane) {
    crx_g<4 - I, 1>(cx,  sx,  amp, lane);
    cry_g<8 - I, 1>(cy1, sy1, amp, lane);
    crz_g<4 - I, 0>(cz,  sz,  amp, lane);
    cry_g<8 - I, 0>(cy2, sy2, amp, lane);
    sel3m<I, 4 + I, 7>(gm + 8,  amp, lane);   // strong[0]
    sel3m<7, 4 + I, 8>(gm + 32, amp, lane);   // strong[1]
}

// ---------- kernel A': tiny prep (gate table + zero gsum/gcnt) ----------
// Replaces the old 65-block MLP kernel; the feature MLPs moved into kernel B.
__global__ void prep_kernel(const float* __restrict__ strong, const float* __restrict__ inits,
                            const float* __restrict__ update,
                            float* __restrict__ gm, float* __restrict__ zbuf, int nzero) {
    int j = threadIdx.x;
    if (j < 4) {
        gm[2 * j]     = cosf(0.5f * inits[j]);
        gm[2 * j + 1] = sinf(0.5f * inits[j]);
    } else if (j < 13) {
        const float* w;
        if (j < 7)       w = strong + (j - 4) * 3;
        else if (j < 10) w = strong + 9 + (j - 7) * 3;
        else             w = update + (j - 10) * 3;
        M4 M = mrot(w[0], w[1], w[2]);
        float* o = gm + 8 + (j - 4) * 8;
        o[0] = M.u00.x; o[1] = M.u00.y; o[2] = M.u01.x; o[3] = M.u01.y;
        o[4] = M.u10.x; o[5] = M.u10.y; o[6] = M.u11.x; o[7] = M.u11.y;
    }
    for (int i = j; i < nzero; i += 64) zbuf[i] = 0.f;
}

// ---------- kernel B: fused feature-MLPs + PQC + update-MLP + pooling ----------
// One wave per sample. The node/edge MLPs are computed in-wave (hidden unit j
// on lane j and lane j+64), removing the old kernel-A global roundtrip. The 14
// tanh+trig evaluations run lane-parallel (lane 2r+ch owns (row r, channel ch)),
// then broadcast via shfl. Head stays a separate kernel (R5 lesson: no fences).
#define MAX_GRAPHS 64
__global__ __launch_bounds__(256) void pqc_fused_kernel(
        const float* __restrict__ node_feat, const float* __restrict__ edge_attr,
        const float* __restrict__ Wn1, const float* __restrict__ bn1,
        const float* __restrict__ Wn2, const float* __restrict__ bn2,
        const float* __restrict__ We1, const float* __restrict__ be1,
        const float* __restrict__ We2, const float* __restrict__ be2,
        const int* __restrict__ subgraphs, const int* __restrict__ edge_ids,
        const int* __restrict__ batch, const float* __restrict__ gm,
        const float* __restrict__ Wu1, const float* __restrict__ bu1,
        const float* __restrict__ Wu2, const float* __restrict__ bu2,
        float* __restrict__ gsum, float* __restrict__ gcnt,
        int ntot, int ngraphs) {
    __shared__ float bins[3 * MAX_GRAPHS];
    for (int i = threadIdx.x; i < 3 * ngraphs; i += 256) bins[i] = 0.f;
    __syncthreads();

    int wave = threadIdx.x >> 6;
    int lane = threadIdx.x & 63;
    int s = blockIdx.x * 4 + wave;
    bool active = s < ntot;

    if (active) {
        int j1 = lane, j2 = lane + 64;

        // ---- per-lane weight preloads (L2-hot, shared by all blocks) ----
        float wn1a[8], wn1b[8];
#pragma unroll
        for (int k = 0; k < 8; k++) { wn1a[k] = Wn1[k * 128 + j1]; wn1b[k] = Wn1[k * 128 + j2]; }
        float bn1a = bn1[j1], bn1b = bn1[j2];
        float wn2a0 = Wn2[2 * j1], wn2a1 = Wn2[2 * j1 + 1];
        float wn2b0 = Wn2[2 * j2], wn2b1 = Wn2[2 * j2 + 1];
        float we1a[4], we1b[4];
#pragma unroll
        for (int k = 0; k < 4; k++) { we1a[k] = We1[k * 128 + j1]; we1b[k] = We1[k * 128 + j2]; }
        float be1a = be1[j1], be1b = be1[j2];
        float we2a0 = We2[2 * j1], we2a1 = We2[2 * j1 + 1];
        float we2b0 = We2[2 * j2], we2b1 = We2[2 * j2 + 1];

        // ---- sample indices ----
        const int4 sg = *reinterpret_cast<const int4*>(subgraphs + (size_t)s * 4);
        int cidx = sg.x;
        int nid[4] = {sg.x, sg.y, sg.z, sg.w};
        int eid[3];
#pragma unroll
        for (int j = 0; j < 3; j++) eid[j] = edge_ids[s * 3 + j];

        // ---- feature MLP partials: rows 0..2 edges, 3..6 nodes ----
        float o0a[7], o1a[7];
#pragma unroll
        for (int j = 0; j < 3; j++) {
            const float4 f = *reinterpret_cast<const float4*>(edge_attr + (size_t)eid[j] * 4);
            float h1 = be1a + f.x * we1a[0] + f.y * we1a[1] + f.z * we1a[2] + f.w * we1a[3];
            float h2 = be1b + f.x * we1b[0] + f.y * we1b[1] + f.z * we1b[2] + f.w * we1b[3];
            h1 = h1 > 0.f ? h1 : 0.01f * h1;
            h2 = h2 > 0.f ? h2 : 0.01f * h2;
            o0a[j] = h1 * we2a0 + h2 * we2b0;
            o1a[j] = h1 * we2a1 + h2 * we2b1;
        }
#pragma unroll
        for (int j = 0; j < 4; j++) {
            const float4* nf = reinterpret_cast<const float4*>(node_feat + (size_t)nid[j] * 8);
            const float4 fa = nf[0], fb = nf[1];
            float h1 = bn1a + fa.x * wn1a[0] + fa.y * wn1a[1] + fa.z * wn1a[2] + fa.w * wn1a[3]
                            + fb.x * wn1a[4] + fb.y * wn1a[5] + fb.z * wn1a[6] + fb.w * wn1a[7];
            float h2 = bn1b + fa.x * wn1b[0] + fa.y * wn1b[1] + fa.z * wn1b[2] + fa.w * wn1b[3]
                            + fb.x * wn1b[4] + fb.y * wn1b[5] + fb.z * wn1b[6] + fb.w * wn1b[7];
            h1 = h1 > 0.f ? h1 : 0.01f * h1;
            h2 = h2 > 0.f ? h2 : 0.01f * h2;
            o0a[3 + j] = h1 * wn2a0 + h2 * wn2b0;
            o1a[3 + j] = h1 * wn2a1 + h2 * wn2b1;
        }
        // butterfly-reduce all 14 partial sums across the wave (batched for ILP)
#pragma unroll
        for (int off = 32; off > 0; off >>= 1) {
#pragma unroll
            for (int r = 0; r < 7; r++) {
                o0a[r] += __shfl_xor(o0a[r], off, 64);
                o1a[r] += __shfl_xor(o1a[r], off, 64);
            }
        }

        // ---- lane-parallel tanh + half-angle trig: lane 2r+ch owns (row r, ch) ----
        float be2_0 = be2[0], be2_1 = be2[1];
        float bn2_0 = bn2[0], bn2_1 = bn2[1];
        int rr = lane >> 1;
        bool ch1 = lane & 1;
        float v = o1a[6];
#pragma unroll
        for (int q = 0; q < 7; q++)
            if (rr == q) v = ch1 ? o1a[q] : o0a[q];
        float bias = (lane < 6) ? (ch1 ? be2_1 : be2_0) : (ch1 ? bn2_1 : bn2_0);
        float t  = tanhf(v + bias) * PI_F;   // full angle (rows*ch), valid on lanes 0..13
        float ah = 0.5f * t;
        float ca = __cosf(ah), sa = __sinf(ah);

        // broadcast trig of all 7 rows x 2 channels to every lane
        float c0[7], s0[7], c1[7], s1[7];
#pragma unroll
        for (int w = 0; w < 7; w++) {
            c0[w] = __shfl(ca, 2 * w, 64);
            s0[w] = __shfl(sa, 2 * w, 64);
            c1[w] = __shfl(ca, 2 * w + 1, 64);
            s1[w] = __shfl(sa, 2 * w + 1, 64);
        }
        float f0 = __shfl(t, 6, 64);   // ang[3][0] = x[cidx].0
        float f1 = __shfl(t, 7, 64);   // ang[3][1] = x[cidx].1

        // ---- encoding layer on |0..0>: closed-form product state ----
        float2 c = make_float2(1.f, 0.f);
#pragma unroll
        for (int w = 0; w < 6; w++) {
            float2 v0 = make_float2(c0[w] * c1[w], -c0[w] * s1[w]);
            float2 v1 = make_float2(s0[w] * c1[w],  s0[w] * s1[w]);
            int bit = (lane >> (5 - w)) & 1;
            c = cmul2(c, bit ? v1 : v0);
        }
        float2 amp[8];
#pragma unroll
        for (int r = 0; r < 8; r++) amp[r] = make_float2(0.f, 0.f);
        amp[0] = cmul2(c, make_float2(c0[6] * c1[6], -c0[6] * s1[6]));
        amp[4] = cmul2(c, make_float2(s0[6] * c1[6],  s0[6] * s1[6]));

        // ---- PQC ----
        float cx  = gm[0], sx  = gm[1];
        float cy1 = gm[2], sy1 = gm[3];
        float cz  = gm[4], sz  = gm[5];
        float cy2 = gm[6], sy2 = gm[7];

        block_i<0>(amp, cx, sx, cy1, sy1, cz, sz, cy2, sy2, gm, lane);
        block_i<1>(amp, cx, sx, cy1, sy1, cz, sz, cy2, sy2, gm, lane);
        block_i<2>(amp, cx, sx, cy1, sy1, cz, sz, cy2, sy2, gm, lane);
        sel3m<3, 7, 8>(gm + 56, amp, lane);

        // <X_3>: butterfly so ALL lanes hold the expval
        float acc = 0.f;
#pragma unroll
        for (int r = 0; r < 8; r++) {
            float2 o = shflx(amp[r], 4);
            acc += amp[r].x * o.x + amp[r].y * o.y;
        }
        for (int off = 32; off > 0; off >>= 1) acc += __shfl_xor(acc, off, 64);

        // ---- update MLP [f0,f1,acc] -> 128 -> 2, wave-parallel ----
        float h1 = bu1[j1] + f0 * Wu1[j1] + f1 * Wu1[128 + j1] + acc * Wu1[256 + j1];
        float h2 = bu1[j2] + f0 * Wu1[j2] + f1 * Wu1[128 + j2] + acc * Wu1[256 + j2];
        h1 = h1 > 0.f ? h1 : 0.01f * h1;
        h2 = h2 > 0.f ? h2 : 0.01f * h2;
        float o0 = h1 * Wu2[2 * j1]     + h2 * Wu2[2 * j2];
        float o1 = h1 * Wu2[2 * j1 + 1] + h2 * Wu2[2 * j2 + 1];
        for (int off = 32; off > 0; off >>= 1) {
            o0 += __shfl_down(o0, off, 64);
            o1 += __shfl_down(o1, off, 64);
        }

        // ---- pooling contribution: x[s] (pre-update) + scattered update ----
        float xs0 = f0, xs1 = f1;
        if (cidx != s) {
            // generic fallback (cold; never taken for this input layout):
            // recompute the node MLP for row s with fresh loads
            const float4* nf = reinterpret_cast<const float4*>(node_feat + (size_t)s * 8);
            const float4 fa = nf[0], fb = nf[1];
            float g1 = bn1[j1], g2 = bn1[j2];
            const float fv[8] = {fa.x, fa.y, fa.z, fa.w, fb.x, fb.y, fb.z, fb.w};
#pragma unroll
            for (int k = 0; k < 8; k++) {
                g1 += fv[k] * Wn1[k * 128 + j1];
                g2 += fv[k] * Wn1[k * 128 + j2];
            }
            g1 = g1 > 0.f ? g1 : 0.01f * g1;
            g2 = g2 > 0.f ? g2 : 0.01f * g2;
            float p0 = g1 * Wn2[2 * j1] + g2 * Wn2[2 * j2];
            float p1 = g1 * Wn2[2 * j1 + 1] + g2 * Wn2[2 * j2 + 1];
            for (int off = 32; off > 0; off >>= 1) {
                p0 += __shfl_xor(p0, off, 64);
                p1 += __shfl_xor(p1, off, 64);
            }
            xs0 = tanhf(p0 + bn2_0) * PI_F;
            xs1 = tanhf(p1 + bn2_1) * PI_F;
        }

        if (lane == 0) {
            o0 += bu2[0]; o1 += bu2[1];
            int bs = batch[s], bc = batch[cidx];
            atomicAdd(&bins[3 * bs + 0], xs0);
            atomicAdd(&bins[3 * bs + 1], xs1);
            atomicAdd(&bins[3 * bs + 2], 1.f);
            atomicAdd(&bins[3 * bc + 0], o0);
            atomicAdd(&bins[3 * bc + 1], o1);
        }
    }
    __syncthreads();

    // flush non-zero bins (typically 1 graph per block)
    for (int i = threadIdx.x; i < ngraphs; i += 256) {
        float s0 = bins[3 * i + 0], s1 = bins[3 * i + 1], sc = bins[3 * i + 2];
        if (s0 != 0.f || s1 != 0.f || sc != 0.f) {
            atomicAdd(&gsum[2 * i + 0], s0);
            atomicAdd(&gsum[2 * i + 1], s1);
            atomicAdd(&gcnt[i], sc);
        }
    }
}

// ---------- kernel C: g = gsum/gcnt; out = mlp(g, 2->2->2) ----------
__global__ void head_kernel(const float* __restrict__ gsum, const float* __restrict__ gcnt,
                            const float* __restrict__ Wh1, const float* __restrict__ bh1,
                            const float* __restrict__ Wh2, const float* __restrict__ bh2,
                            float* __restrict__ out, int ngraphs) {
    int g = threadIdx.x;
    if (g >= ngraphs) return;
    float c = gcnt[g];
    float g0 = gsum[2 * g + 0] / c;
    float g1 = gsum[2 * g + 1] / c;
    float h0 = g0 * Wh1[0] + g1 * Wh1[2] + bh1[0];
    float h1 = g0 * Wh1[1] + g1 * Wh1[3] + bh1[1];
    h0 = h0 > 0.f ? h0 : 0.01f * h0;
    h1 = h1 > 0.f ? h1 : 0.01f * h1;
    out[2 * g + 0] = h0 * Wh2[0] + h1 * Wh2[2] + bh2[0];
    out[2 * g + 1] = h0 * Wh2[1] + h1 * Wh2[3] + bh2[1];
}

extern "C" void kernel_launch(void* const* d_in, const int* in_sizes, int n_in,
                              void* d_out, int out_size, void* d_ws, size_t ws_size,
                              hipStream_t stream) {
    const float* node_feat = (const float*)d_in[0];   // (N, 8)
    const float* edge_attr = (const float*)d_in[1];   // (3N, 4)
    const float* Wn1 = (const float*)d_in[2];
    const float* bn1 = (const float*)d_in[3];
    const float* Wn2 = (const float*)d_in[4];
    const float* bn2 = (const float*)d_in[5];
    const float* We1 = (const float*)d_in[6];
    const float* be1 = (const float*)d_in[7];
    const float* We2 = (const float*)d_in[8];
    const float* be2 = (const float*)d_in[9];
    const float* strong = (const float*)d_in[10];     // (2,1,3,3)
    const float* inits  = (const float*)d_in[11];     // (1,4)
    const float* update = (const float*)d_in[12];     // (1,3,3)
    const float* Wu1 = (const float*)d_in[13];
    const float* bu1 = (const float*)d_in[14];
    const float* Wu2 = (const float*)d_in[15];
    const float* bu2 = (const float*)d_in[16];
    const float* Wh1 = (const float*)d_in[17];
    const float* bh1 = (const float*)d_in[18];
    const float* Wh2 = (const float*)d_in[19];
    const float* bh2 = (const float*)d_in[20];
    const int* subgraphs = (const int*)d_in[21];      // (N, 4)
    const int* edge_ids  = (const int*)d_in[22];      // (N, 3)
    const int* batch     = (const int*)d_in[23];      // (N,)

    const int N  = in_sizes[0] / 8;      // 4096 nodes (= samples)
    const int NG = out_size / 2;         // 16 graphs

    // workspace layout (floats)
    float* ws   = (float*)d_ws;
    float* gsum = ws;                    // NG*2
    float* gcnt = gsum + (size_t)NG * 2; // NG       (contiguous with gsum)
    float* gm   = gcnt + NG;             // 80 floats of gate data

    // Kernel A': gate table + zero gsum/gcnt (1 block)
    prep_kernel<<<1, 64, 0, stream>>>(strong, inits, update, gm, gsum, 3 * NG);

    // Kernel B: fused feature-MLPs + PQC + update MLP + pooling
    pqc_fused_kernel<<<(N + 3) / 4, 256, 0, stream>>>(
        node_feat, edge_attr, Wn1, bn1, Wn2, bn2, We1, be1, We2, be2,
        subgraphs, edge_ids, batch, gm, Wu1, bu1, Wu2, bu2,
        gsum, gcnt, N, NG);

    // Kernel C: head
    head_kernel<<<1, 64, 0, stream>>>(gsum, gcnt, Wh1, bh1, Wh2, bh2, (float*)d_out, NG);
}

// Round 3
// 138.303 us; speedup vs baseline: 1.0990x; 1.0265x over previous
//
#include <hip/hip_runtime.h>
#include <math.h>

#define PI_F 3.14159265358979323846f

// ---------- complex helpers (float2 as complex) ----------
__device__ __forceinline__ float2 cmul2(float2 a, float2 b) {
    return make_float2(a.x * b.x - a.y * b.y, a.x * b.y + a.y * b.x);
}
// u*a + v*b
__device__ __forceinline__ float2 cmac2(float2 u, float2 a, float2 v, float2 b) {
    float2 r;
    r.x = u.x * a.x - u.y * a.y + v.x * b.x - v.y * b.y;
    r.y = u.x * a.y + u.y * a.x + v.x * b.y + v.y * b.x;
    return r;
}

struct M4 { float2 u00, u01, u10, u11; };

__device__ __forceinline__ M4 mmul4(const M4& A, const M4& B) {
    M4 R;
    R.u00 = cmac2(A.u00, B.u00, A.u01, B.u10);
    R.u01 = cmac2(A.u00, B.u01, A.u01, B.u11);
    R.u10 = cmac2(A.u10, B.u00, A.u11, B.u10);
    R.u11 = cmac2(A.u10, B.u01, A.u11, B.u11);
    return R;
}
__device__ __forceinline__ M4 mry(float t) {
    float c = cosf(0.5f * t), s = sinf(0.5f * t);
    M4 R; R.u00 = {c, 0}; R.u01 = {-s, 0}; R.u10 = {s, 0}; R.u11 = {c, 0};
    return R;
}
__device__ __forceinline__ M4 mrz(float t) {
    float c = cosf(0.5f * t), s = sinf(0.5f * t);
    M4 R; R.u00 = {c, -s}; R.u01 = {0, 0}; R.u10 = {0, 0}; R.u11 = {c, s};
    return R;
}
// Rot(phi, theta, omega) = RZ(omega) @ RY(theta) @ RZ(phi)
__device__ __forceinline__ M4 mrot(float phi, float th, float om) {
    return mmul4(mmul4(mrz(om), mry(th)), mrz(phi));
}

// ---------- cross-lane xor-exchange ----------
// mask 1,2  -> DPP quad_perm (VALU)
// mask 4,8  -> ds_swizzle (DS pipe, patterns 0x101F/0x201F per ISA doc)
// mask 16,32-> v_permlane16/32_swap with BOTH operands the same register:
//              swaps the register's own row-pairs / halves, i.e. a full
//              xor-16/xor-32 exchange in one VALU op, with no dependence on
//              which operand the ISA treats as "first" (R2 post-mortem: the
//              two-copy + select variant had inverted polarity).
__device__ __forceinline__ float plsw16(float v) {
    asm("v_permlane16_swap_b32 %0, %0" : "+v"(v));
    return v;
}
__device__ __forceinline__ float plsw32(float v) {
    asm("v_permlane32_swap_b32 %0, %0" : "+v"(v));
    return v;
}

template <int MASK>
__device__ __forceinline__ float lxor(float v) {
    if constexpr (MASK == 1)
        return __int_as_float(__builtin_amdgcn_update_dpp(
            0, __float_as_int(v), 0xB1, 0xF, 0xF, true));       // quad_perm [1,0,3,2]
    else if constexpr (MASK == 2)
        return __int_as_float(__builtin_amdgcn_update_dpp(
            0, __float_as_int(v), 0x4E, 0xF, 0xF, true));       // quad_perm [2,3,0,1]
    else if constexpr (MASK == 4)
        return __int_as_float(__builtin_amdgcn_ds_swizzle(__float_as_int(v), 0x101F));
    else if constexpr (MASK == 8)
        return __int_as_float(__builtin_amdgcn_ds_swizzle(__float_as_int(v), 0x201F));
    else if constexpr (MASK == 16)
        return plsw16(v);
    else
        return plsw32(v);
}

template <int MASK>
__device__ __forceinline__ float2 lxor2(float2 v) {
    return make_float2(lxor<MASK>(v.x), lxor<MASK>(v.y));
}

template <int MASK>
__device__ __forceinline__ float rsum(float v) {
    return v + lxor<MASK>(v);
}

// load an M4 from wave-uniform global memory (compiler emits scalar loads)
__device__ __forceinline__ M4 ldm(const float* __restrict__ g) {
    M4 M;
    M.u00 = make_float2(g[0], g[1]); M.u01 = make_float2(g[2], g[3]);
    M.u10 = make_float2(g[4], g[5]); M.u11 = make_float2(g[6], g[7]);
    return M;
}

// ---------- register statevector: idx = lane*8 + r ----------
// idx bit b: b in [0,2] -> register bit b; b in [3,8] -> lane bit (b-3).
// wire w -> idx bit (8-w). Wires 0..5 = lane bits 5..0; wires 6,7,8 = reg bits 2,1,0.

// single-qubit dense gate on register bit TB
template <int TB>
__device__ __forceinline__ void rot_reg(const M4& U, float2 (&amp)[8]) {
#pragma unroll
    for (int r = 0; r < 8; r++)
        if (((r >> TB) & 1) == 0) {
            int r1 = r | (1 << TB);
            float2 a = amp[r], b = amp[r1];
            amp[r]  = cmac2(U.u00, a, U.u01, b);
            amp[r1] = cmac2(U.u10, a, U.u11, b);
        }
}

// single-qubit dense gate on lane bit LB
template <int LB>
__device__ __forceinline__ void rot_lane(const M4& U, float2 (&amp)[8], int lane) {
    bool hi = (lane >> LB) & 1;
    float2 cA = hi ? U.u11 : U.u00;
    float2 cB = hi ? U.u10 : U.u01;
#pragma unroll
    for (int r = 0; r < 8; r++) {
        float2 o = lxor2<(1 << LB)>(amp[r]);
        amp[r] = cmac2(cA, amp[r], cB, o);
    }
}

template <int WIRE>
__device__ __forceinline__ void rot1(const M4& U, float2 (&amp)[8], int lane) {
    constexpr int BIT = 8 - WIRE;
    if constexpr (BIT < 3) rot_reg<BIT>(U, amp);
    else rot_lane<BIT - 3>(U, amp, lane);
}

// ---------- specialized controlled rotations (target = reg bit TB) ----------

// controlled RX: [[c, -i s], [-i s, c]]
template <int CBIT, int TB>
__device__ __forceinline__ void crx_g(float c, float s, float2 (&amp)[8], int lane) {
    if constexpr (CBIT >= 3) {
        bool ct = (lane >> (CBIT - 3)) & 1;
        float cc = ct ? c : 1.f, ss = ct ? s : 0.f;
#pragma unroll
        for (int r = 0; r < 8; r++)
            if (((r >> TB) & 1) == 0) {
                int r1 = r | (1 << TB);
                float2 a = amp[r], b = amp[r1];
                amp[r]  = make_float2(cc * a.x + ss * b.y, cc * a.y - ss * b.x);
                amp[r1] = make_float2(ss * a.y + cc * b.x, cc * b.y - ss * a.x);
            }
    } else {
#pragma unroll
        for (int r = 0; r < 8; r++)
            if (((r >> CBIT) & 1) == 1 && ((r >> TB) & 1) == 0) {
                int r1 = r | (1 << TB);
                float2 a = amp[r], b = amp[r1];
                amp[r]  = make_float2(c * a.x + s * b.y, c * a.y - s * b.x);
                amp[r1] = make_float2(s * a.y + c * b.x, c * b.y - s * a.x);
            }
    }
}

// controlled RY: [[c, -s], [s, c]] (real)
template <int CBIT, int TB>
__device__ __forceinline__ void cry_g(float c, float s, float2 (&amp)[8], int lane) {
    if constexpr (CBIT >= 3) {
        bool ct = (lane >> (CBIT - 3)) & 1;
        float cc = ct ? c : 1.f, ss = ct ? s : 0.f;
#pragma unroll
        for (int r = 0; r < 8; r++)
            if (((r >> TB) & 1) == 0) {
                int r1 = r | (1 << TB);
                float2 a = amp[r], b = amp[r1];
                amp[r]  = make_float2(cc * a.x - ss * b.x, cc * a.y - ss * b.y);
                amp[r1] = make_float2(ss * a.x + cc * b.x, ss * a.y + cc * b.y);
            }
    } else {
#pragma unroll
        for (int r = 0; r < 8; r++)
            if (((r >> CBIT) & 1) == 1 && ((r >> TB) & 1) == 0) {
                int r1 = r | (1 << TB);
                float2 a = amp[r], b = amp[r1];
                amp[r]  = make_float2(c * a.x - s * b.x, c * a.y - s * b.y);
                amp[r1] = make_float2(s * a.x + c * b.x, s * a.y + c * b.y);
            }
    }
}

// controlled RZ: diag(e, conj(e)), e = c - i s
template <int CBIT, int TB>
__device__ __forceinline__ void crz_g(float c, float s, float2 (&amp)[8], int lane) {
    if constexpr (CBIT >= 3) {
        bool ct = (lane >> (CBIT - 3)) & 1;
        float cc = ct ? c : 1.f, ss = ct ? s : 0.f;
#pragma unroll
        for (int r = 0; r < 8; r++)
            if (((r >> TB) & 1) == 0) {
                int r1 = r | (1 << TB);
                float2 a = amp[r], b = amp[r1];
                amp[r]  = make_float2(cc * a.x + ss * a.y, cc * a.y - ss * a.x);
                amp[r1] = make_float2(cc * b.x - ss * b.y, cc * b.y + ss * b.x);
            }
    } else {
#pragma unroll
        for (int r = 0; r < 8; r++)
            if (((r >> CBIT) & 1) == 1 && ((r >> TB) & 1) == 0) {
                int r1 = r | (1 << TB);
                float2 a = amp[r], b = amp[r1];
                amp[r]  = make_float2(c * a.x + s * a.y, c * a.y - s * a.x);
                amp[r1] = make_float2(c * b.x - s * b.y, c * b.y + s * b.x);
            }
    }
}

template <int CW, int TW>
__device__ __forceinline__ void cnotg(float2 (&amp)[8], int lane) {
    constexpr int CBIT = 8 - CW, TBIT = 8 - TW;
    if constexpr (CBIT < 3 && TBIT < 3) {
#pragma unroll
        for (int r = 0; r < 8; r++)
            if (((r >> CBIT) & 1) == 1 && ((r >> TBIT) & 1) == 0) {
                int r1 = r | (1 << TBIT);
                float2 t = amp[r]; amp[r] = amp[r1]; amp[r1] = t;
            }
    } else if constexpr (CBIT >= 3 && TBIT < 3) {
        bool c = (lane >> (CBIT - 3)) & 1;
#pragma unroll
        for (int r = 0; r < 8; r++)
            if (((r >> TBIT) & 1) == 0) {
                int r1 = r | (1 << TBIT);
                float2 t0 = amp[r], t1 = amp[r1];
                amp[r]  = c ? t1 : t0;
                amp[r1] = c ? t0 : t1;
            }
    } else if constexpr (CBIT < 3 && TBIT >= 3) {
#pragma unroll
        for (int r = 0; r < 8; r++)
            if (((r >> CBIT) & 1) == 1) {
                amp[r] = lxor2<(1 << (TBIT - 3))>(amp[r]);
            }
    } else {
        bool c = (lane >> (CBIT - 3)) & 1;
#pragma unroll
        for (int r = 0; r < 8; r++) {
            float2 o = lxor2<(1 << (TBIT - 3))>(amp[r]);
            amp[r] = c ? o : amp[r];
        }
    }
}

// StronglyEntanglingLayers, L=1, 3 wires; gm = 3 precomputed dense Rot matrices
template <int W0, int W1, int W2>
__device__ __forceinline__ void sel3m(const float* __restrict__ gm, float2 (&amp)[8], int lane) {
    rot1<W0>(ldm(gm),      amp, lane);
    rot1<W1>(ldm(gm + 8),  amp, lane);
    rot1<W2>(ldm(gm + 16), amp, lane);
    cnotg<W0, W1>(amp, lane);
    cnotg<W1, W2>(amp, lane);
    cnotg<W2, W0>(amp, lane);
}

// gm layout (floats): [0..7] (c,s) x4 ctrl gates; [8..31] strong[0]; [32..55] strong[1]; [56..79] update
template <int I>
__device__ __forceinline__ void block_i(float2 (&amp)[8], float cx, float sx, float cy1, float sy1,
                                        float cz, float sz, float cy2, float sy2,
                                        const float* __restrict__ gm, int lane) {
    crx_g<4 - I, 1>(cx,  sx,  amp, lane);
    cry_g<8 - I, 1>(cy1, sy1, amp, lane);
    crz_g<4 - I, 0>(cz,  sz,  amp, lane);
    cry_g<8 - I, 0>(cy2, sy2, amp, lane);
    sel3m<I, 4 + I, 7>(gm + 8,  amp, lane);   // strong[0]
    sel3m<7, 4 + I, 8>(gm + 32, amp, lane);   // strong[1]
}

// ---------- kernel A': tiny prep (gate table + zero gsum/gcnt) ----------
__global__ void prep_kernel(const float* __restrict__ strong, const float* __restrict__ inits,
                            const float* __restrict__ update,
                            float* __restrict__ gm, float* __restrict__ zbuf, int nzero) {
    int j = threadIdx.x;
    if (j < 4) {
        gm[2 * j]     = cosf(0.5f * inits[j]);
        gm[2 * j + 1] = sinf(0.5f * inits[j]);
    } else if (j < 13) {
        const float* w;
        if (j < 7)       w = strong + (j - 4) * 3;
        else if (j < 10) w = strong + 9 + (j - 7) * 3;
        else             w = update + (j - 10) * 3;
        M4 M = mrot(w[0], w[1], w[2]);
        float* o = gm + 8 + (j - 4) * 8;
        o[0] = M.u00.x; o[1] = M.u00.y; o[2] = M.u01.x; o[3] = M.u01.y;
        o[4] = M.u10.x; o[5] = M.u10.y; o[6] = M.u11.x; o[7] = M.u11.y;
    }
    for (int i = j; i < nzero; i += 64) zbuf[i] = 0.f;
}

// ---------- kernel B: fused feature-MLPs + PQC + update-MLP + pooling ----------
// One wave per sample. Cross-lane ops use DPP/permlane_swap (VALU) wherever the
// xor mask allows; only xor-4/8 and broadcasts touch the DS pipe. The 14 MLP
// outputs are reduced with a value-packing fold that lands sum j on lane j.
#define MAX_GRAPHS 64
__global__ __launch_bounds__(256) void pqc_fused_kernel(
        const float* __restrict__ node_feat, const float* __restrict__ edge_attr,
        const float* __restrict__ Wn1, const float* __restrict__ bn1,
        const float* __restrict__ Wn2, const float* __restrict__ bn2,
        const float* __restrict__ We1, const float* __restrict__ be1,
        const float* __restrict__ We2, const float* __restrict__ be2,
        const int* __restrict__ subgraphs, const int* __restrict__ edge_ids,
        const int* __restrict__ batch, const float* __restrict__ gm,
        const float* __restrict__ Wu1, const float* __restrict__ bu1,
        const float* __restrict__ Wu2, const float* __restrict__ bu2,
        float* __restrict__ gsum, float* __restrict__ gcnt,
        int ntot, int ngraphs) {
    __shared__ float bins[3 * MAX_GRAPHS];
    for (int i = threadIdx.x; i < 3 * ngraphs; i += 256) bins[i] = 0.f;
    __syncthreads();

    int wave = threadIdx.x >> 6;
    int lane = threadIdx.x & 63;
    int s = blockIdx.x * 4 + wave;
    bool active = s < ntot;

    if (active) {
        int j1 = lane, j2 = lane + 64;

        // ---- per-lane weight preloads (L2-hot, shared by all blocks) ----
        float wn1a[8], wn1b[8];
#pragma unroll
        for (int k = 0; k < 8; k++) { wn1a[k] = Wn1[k * 128 + j1]; wn1b[k] = Wn1[k * 128 + j2]; }
        float bn1a = bn1[j1], bn1b = bn1[j2];
        float wn2a0 = Wn2[2 * j1], wn2a1 = Wn2[2 * j1 + 1];
        float wn2b0 = Wn2[2 * j2], wn2b1 = Wn2[2 * j2 + 1];
        float we1a[4], we1b[4];
#pragma unroll
        for (int k = 0; k < 4; k++) { we1a[k] = We1[k * 128 + j1]; we1b[k] = We1[k * 128 + j2]; }
        float be1a = be1[j1], be1b = be1[j2];
        float we2a0 = We2[2 * j1], we2a1 = We2[2 * j1 + 1];
        float we2b0 = We2[2 * j2], we2b1 = We2[2 * j2 + 1];

        // ---- sample indices ----
        const int4 sg = *reinterpret_cast<const int4*>(subgraphs + (size_t)s * 4);
        int cidx = sg.x;
        int nid[4] = {sg.x, sg.y, sg.z, sg.w};
        int eid[3];
#pragma unroll
        for (int j = 0; j < 3; j++) eid[j] = edge_ids[s * 3 + j];

        // ---- feature MLP partials: value idx 2r+ch, rows 0..2 edges, 3..6 nodes ----
        float o0a[7], o1a[7];
#pragma unroll
        for (int j = 0; j < 3; j++) {
            const float4 f = *reinterpret_cast<const float4*>(edge_attr + (size_t)eid[j] * 4);
            float h1 = be1a + f.x * we1a[0] + f.y * we1a[1] + f.z * we1a[2] + f.w * we1a[3];
            float h2 = be1b + f.x * we1b[0] + f.y * we1b[1] + f.z * we1b[2] + f.w * we1b[3];
            h1 = h1 > 0.f ? h1 : 0.01f * h1;
            h2 = h2 > 0.f ? h2 : 0.01f * h2;
            o0a[j] = h1 * we2a0 + h2 * we2b0;
            o1a[j] = h1 * we2a1 + h2 * we2b1;
        }
#pragma unroll
        for (int j = 0; j < 4; j++) {
            const float4* nf = reinterpret_cast<const float4*>(node_feat + (size_t)nid[j] * 8);
            const float4 fa = nf[0], fb = nf[1];
            float h1 = bn1a + fa.x * wn1a[0] + fa.y * wn1a[1] + fa.z * wn1a[2] + fa.w * wn1a[3]
                            + fb.x * wn1a[4] + fb.y * wn1a[5] + fb.z * wn1a[6] + fb.w * wn1a[7];
            float h2 = bn1b + fa.x * wn1b[0] + fa.y * wn1b[1] + fa.z * wn1b[2] + fa.w * wn1b[3]
                            + fb.x * wn1b[4] + fb.y * wn1b[5] + fb.z * wn1b[6] + fb.w * wn1b[7];
            h1 = h1 > 0.f ? h1 : 0.01f * h1;
            h2 = h2 > 0.f ? h2 : 0.01f * h2;
            o0a[3 + j] = h1 * wn2a0 + h2 * wn2b0;
            o1a[3 + j] = h1 * wn2a1 + h2 * wn2b1;
        }

        // ---- value-packing fold: 14 sums -> lane j holds value j (j = 2r+ch) ----
        // level 1 (mask 1, DPP): ch bit -> lane bit 0
        float L1[7];
#pragma unroll
        for (int i = 0; i < 7; i++) {
            float r0 = rsum<1>(o0a[i]);
            float r1 = rsum<1>(o1a[i]);
            L1[i] = (lane & 1) ? r1 : r0;
        }
        // level 2 (mask 2, DPP): r bit0 -> lane bit 1
        float L2[4];
#pragma unroll
        for (int i = 0; i < 3; i++) {
            float r0 = rsum<2>(L1[2 * i]);
            float r1 = rsum<2>(L1[2 * i + 1]);
            L2[i] = (lane & 2) ? r1 : r0;
        }
        L2[3] = rsum<2>(L1[6]);                  // r=7 slot unused
        // level 3 (mask 4, swizzle): r bit1 -> lane bit 2
        float L3[2];
#pragma unroll
        for (int i = 0; i < 2; i++) {
            float r0 = rsum<4>(L2[2 * i]);
            float r1 = rsum<4>(L2[2 * i + 1]);
            L3[i] = (lane & 4) ? r1 : r0;
        }
        // level 4 (mask 8, swizzle): r bit2 -> lane bit 3
        float T;
        {
            float r0 = rsum<8>(L3[0]);
            float r1 = rsum<8>(L3[1]);
            T = (lane & 8) ? r1 : r0;
        }
        // levels 5,6 (permlane_swap): finish the 64-lane sum
        T = rsum<16>(T);
        T = rsum<32>(T);

        // ---- tanh + half-angle trig on designated lanes (0..13) ----
        float be2_0 = be2[0], be2_1 = be2[1];
        float bn2_0 = bn2[0], bn2_1 = bn2[1];
        float bias = (lane < 6) ? ((lane & 1) ? be2_1 : be2_0)
                                : ((lane & 1) ? bn2_1 : bn2_0);
        float t  = tanhf(T + bias) * PI_F;   // full angle, valid on lanes 0..13
        float ah = 0.5f * t;
        float ca = __cosf(ah), sa = __sinf(ah);

        // broadcast trig of all 7 rows x 2 channels to every lane
        float c0[7], s0[7], c1[7], s1[7];
#pragma unroll
        for (int w = 0; w < 7; w++) {
            c0[w] = __shfl(ca, 2 * w, 64);
            s0[w] = __shfl(sa, 2 * w, 64);
            c1[w] = __shfl(ca, 2 * w + 1, 64);
            s1[w] = __shfl(sa, 2 * w + 1, 64);
        }
        float f0 = __shfl(t, 6, 64);   // ang[3][0] = x[cidx].0
        float f1 = __shfl(t, 7, 64);   // ang[3][1] = x[cidx].1

        // ---- encoding layer on |0..0>: closed-form product state ----
        float2 c = make_float2(1.f, 0.f);
#pragma unroll
        for (int w = 0; w < 6; w++) {
            float2 v0 = make_float2(c0[w] * c1[w], -c0[w] * s1[w]);
            float2 v1 = make_float2(s0[w] * c1[w],  s0[w] * s1[w]);
            int bit = (lane >> (5 - w)) & 1;
            c = cmul2(c, bit ? v1 : v0);
        }
        float2 amp[8];
#pragma unroll
        for (int r = 0; r < 8; r++) amp[r] = make_float2(0.f, 0.f);
        amp[0] = cmul2(c, make_float2(c0[6] * c1[6], -c0[6] * s1[6]));
        amp[4] = cmul2(c, make_float2(s0[6] * c1[6],  s0[6] * s1[6]));

        // ---- PQC ----
        float cx  = gm[0], sx  = gm[1];
        float cy1 = gm[2], sy1 = gm[3];
        float cz  = gm[4], sz  = gm[5];
        float cy2 = gm[6], sy2 = gm[7];

        block_i<0>(amp, cx, sx, cy1, sy1, cz, sz, cy2, sy2, gm, lane);
        block_i<1>(amp, cx, sx, cy1, sy1, cz, sz, cy2, sy2, gm, lane);
        block_i<2>(amp, cx, sx, cy1, sy1, cz, sz, cy2, sy2, gm, lane);
        sel3m<3, 7, 8>(gm + 56, amp, lane);

        // <X_3>: pair product (mask 4) then full-wave butterfly on cheap pipes
        float acc = 0.f;
#pragma unroll
        for (int r = 0; r < 8; r++) {
            float2 o = lxor2<4>(amp[r]);
            acc += amp[r].x * o.x + amp[r].y * o.y;
        }
        acc = rsum<1>(acc);
        acc = rsum<2>(acc);
        acc = rsum<4>(acc);
        acc = rsum<8>(acc);
        acc = rsum<16>(acc);
        acc = rsum<32>(acc);

        // ---- update MLP [f0,f1,acc] -> 128 -> 2, wave-parallel ----
        float h1 = bu1[j1] + f0 * Wu1[j1] + f1 * Wu1[128 + j1] + acc * Wu1[256 + j1];
        float h2 = bu1[j2] + f0 * Wu1[j2] + f1 * Wu1[128 + j2] + acc * Wu1[256 + j2];
        h1 = h1 > 0.f ? h1 : 0.01f * h1;
        h2 = h2 > 0.f ? h2 : 0.01f * h2;
        float o0 = h1 * Wu2[2 * j1]     + h2 * Wu2[2 * j2];
        float o1 = h1 * Wu2[2 * j1 + 1] + h2 * Wu2[2 * j2 + 1];
        o0 = rsum<1>(o0);  o1 = rsum<1>(o1);
        o0 = rsum<2>(o0);  o1 = rsum<2>(o1);
        o0 = rsum<4>(o0);  o1 = rsum<4>(o1);
        o0 = rsum<8>(o0);  o1 = rsum<8>(o1);
        o0 = rsum<16>(o0); o1 = rsum<16>(o1);
        o0 = rsum<32>(o0); o1 = rsum<32>(o1);

        // ---- pooling contribution: x[s] (pre-update) + scattered update ----
        float xs0 = f0, xs1 = f1;
        if (cidx != s) {
            // generic fallback (cold; never taken for this input layout)
            const float4* nf = reinterpret_cast<const float4*>(node_feat + (size_t)s * 8);
            const float4 fa = nf[0], fb = nf[1];
            float g1 = bn1[j1], g2 = bn1[j2];
            const float fv[8] = {fa.x, fa.y, fa.z, fa.w, fb.x, fb.y, fb.z, fb.w};
#pragma unroll
            for (int k = 0; k < 8; k++) {
                g1 += fv[k] * Wn1[k * 128 + j1];
                g2 += fv[k] * Wn1[k * 128 + j2];
            }
            g1 = g1 > 0.f ? g1 : 0.01f * g1;
            g2 = g2 > 0.f ? g2 : 0.01f * g2;
            float p0 = g1 * Wn2[2 * j1] + g2 * Wn2[2 * j2];
            float p1 = g1 * Wn2[2 * j1 + 1] + g2 * Wn2[2 * j2 + 1];
            for (int off = 32; off > 0; off >>= 1) {
                p0 += __shfl_xor(p0, off, 64);
                p1 += __shfl_xor(p1, off, 64);
            }
            xs0 = tanhf(p0 + bn2_0) * PI_F;
            xs1 = tanhf(p1 + bn2_1) * PI_F;
        }

        if (lane == 0) {
            o0 += bu2[0]; o1 += bu2[1];
            int bs = batch[s], bc = batch[cidx];
            atomicAdd(&bins[3 * bs + 0], xs0);
            atomicAdd(&bins[3 * bs + 1], xs1);
            atomicAdd(&bins[3 * bs + 2], 1.f);
            atomicAdd(&bins[3 * bc + 0], o0);
            atomicAdd(&bins[3 * bc + 1], o1);
        }
    }
    __syncthreads();

    // flush non-zero bins (typically 1 graph per block)
    for (int i = threadIdx.x; i < ngraphs; i += 256) {
        float s0 = bins[3 * i + 0], s1 = bins[3 * i + 1], sc = bins[3 * i + 2];
        if (s0 != 0.f || s1 != 0.f || sc != 0.f) {
            atomicAdd(&gsum[2 * i + 0], s0);
            atomicAdd(&gsum[2 * i + 1], s1);
            atomicAdd(&gcnt[i], sc);
        }
    }
}

// ---------- kernel C: g = gsum/gcnt; out = mlp(g, 2->2->2) ----------
__global__ void head_kernel(const float* __restrict__ gsum, const float* __restrict__ gcnt,
                            const float* __restrict__ Wh1, const float* __restrict__ bh1,
                            const float* __restrict__ Wh2, const float* __restrict__ bh2,
                            float* __restrict__ out, int ngraphs) {
    int g = threadIdx.x;
    if (g >= ngraphs) return;
    float c = gcnt[g];
    float g0 = gsum[2 * g + 0] / c;
    float g1 = gsum[2 * g + 1] / c;
    float h0 = g0 * Wh1[0] + g1 * Wh1[2] + bh1[0];
    float h1 = g0 * Wh1[1] + g1 * Wh1[3] + bh1[1];
    h0 = h0 > 0.f ? h0 : 0.01f * h0;
    h1 = h1 > 0.f ? h1 : 0.01f * h1;
    out[2 * g + 0] = h0 * Wh2[0] + h1 * Wh2[2] + bh2[0];
    out[2 * g + 1] = h0 * Wh2[1] + h1 * Wh2[3] + bh2[1];
}

extern "C" void kernel_launch(void* const* d_in, const int* in_sizes, int n_in,
                              void* d_out, int out_size, void* d_ws, size_t ws_size,
                              hipStream_t stream) {
    const float* node_feat = (const float*)d_in[0];   // (N, 8)
    const float* edge_attr = (const float*)d_in[1];   // (3N, 4)
    const float* Wn1 = (const float*)d_in[2];
    const float* bn1 = (const float*)d_in[3];
    const float* Wn2 = (const float*)d_in[4];
    const float* bn2 = (const float*)d_in[5];
    const float* We1 = (const float*)d_in[6];
    const float* be1 = (const float*)d_in[7];
    const float* We2 = (const float*)d_in[8];
    const float* be2 = (const float*)d_in[9];
    const float* strong = (const float*)d_in[10];     // (2,1,3,3)
    const float* inits  = (const float*)d_in[11];     // (1,4)
    const float* update = (const float*)d_in[12];     // (1,3,3)
    const float* Wu1 = (const float*)d_in[13];
    const float* bu1 = (const float*)d_in[14];
    const float* Wu2 = (const float*)d_in[15];
    const float* bu2 = (const float*)d_in[16];
    const float* Wh1 = (const float*)d_in[17];
    const float* bh1 = (const float*)d_in[18];
    const float* Wh2 = (const float*)d_in[19];
    const float* bh2 = (const float*)d_in[20];
    const int* subgraphs = (const int*)d_in[21];      // (N, 4)
    const int* edge_ids  = (const int*)d_in[22];      // (N, 3)
    const int* batch     = (const int*)d_in[23];      // (N,)

    const int N  = in_sizes[0] / 8;      // 4096 nodes (= samples)
    const int NG = out_size / 2;         // 16 graphs

    // workspace layout (floats)
    float* ws   = (float*)d_ws;
    float* gsum = ws;                    // NG*2
    float* gcnt = gsum + (size_t)NG * 2; // NG       (contiguous with gsum)
    float* gm   = gcnt + NG;             // 80 floats of gate data

    // Kernel A': gate table + zero gsum/gcnt (1 block)
    prep_kernel<<<1, 64, 0, stream>>>(strong, inits, update, gm, gsum, 3 * NG);

    // Kernel B: fused feature-MLPs + PQC + update MLP + pooling
    pqc_fused_kernel<<<(N + 3) / 4, 256, 0, stream>>>(
        node_feat, edge_attr, Wn1, bn1, Wn2, bn2, We1, be1, We2, be2,
        subgraphs, edge_ids, batch, gm, Wu1, bu1, Wu2, bu2,
        gsum, gcnt, N, NG);

    // Kernel C: head
    head_kernel<<<1, 64, 0, stream>>>(gsum, gcnt, Wh1, bh1, Wh2, bh2, (float*)d_out, NG);
}

// Round 4
// 134.870 us; speedup vs baseline: 1.1270x; 1.0255x over previous
//
#include <hip/hip_runtime.h>
#include <math.h>

#define PI_F 3.14159265358979323846f

// ---------- complex helpers (float2 as complex) ----------
__device__ __forceinline__ float2 cmul2(float2 a, float2 b) {
    return make_float2(a.x * b.x - a.y * b.y, a.x * b.y + a.y * b.x);
}
// u*a + v*b
__device__ __forceinline__ float2 cmac2(float2 u, float2 a, float2 v, float2 b) {
    float2 r;
    r.x = u.x * a.x - u.y * a.y + v.x * b.x - v.y * b.y;
    r.y = u.x * a.y + u.y * a.x + v.x * b.y + v.y * b.x;
    return r;
}

struct M4 { float2 u00, u01, u10, u11; };

__device__ __forceinline__ M4 mmul4(const M4& A, const M4& B) {
    M4 R;
    R.u00 = cmac2(A.u00, B.u00, A.u01, B.u10);
    R.u01 = cmac2(A.u00, B.u01, A.u01, B.u11);
    R.u10 = cmac2(A.u10, B.u00, A.u11, B.u10);
    R.u11 = cmac2(A.u10, B.u01, A.u11, B.u11);
    return R;
}
__device__ __forceinline__ M4 mry(float t) {
    float c = cosf(0.5f * t), s = sinf(0.5f * t);
    M4 R; R.u00 = {c, 0}; R.u01 = {-s, 0}; R.u10 = {s, 0}; R.u11 = {c, 0};
    return R;
}
__device__ __forceinline__ M4 mrz(float t) {
    float c = cosf(0.5f * t), s = sinf(0.5f * t);
    M4 R; R.u00 = {c, -s}; R.u01 = {0, 0}; R.u10 = {0, 0}; R.u11 = {c, s};
    return R;
}
// Rot(phi, theta, omega) = RZ(omega) @ RY(theta) @ RZ(phi)
__device__ __forceinline__ M4 mrot(float phi, float th, float om) {
    return mmul4(mmul4(mrz(om), mry(th)), mrz(phi));
}

// fast tanh on the trans pipe: 1 - 2/(e^{2x}+1); exact to ~1e-6, saturates
// correctly at +-1 for |x| large (expf(inf)=inf -> 1, expf(-inf)=0 -> -1).
__device__ __forceinline__ float fast_tanh(float x) {
    float e = __expf(2.f * x);
    return 1.f - 2.f / (e + 1.f);
}

// ---------- cross-lane xor-exchange (verified R3) ----------
// mask 1,2  -> DPP quad_perm (VALU)
// mask 4,8  -> ds_swizzle (DS pipe)
// mask 16,32-> v_permlane16/32_swap, both operands the same register (VALU)
__device__ __forceinline__ float plsw16(float v) {
    asm("v_permlane16_swap_b32 %0, %0" : "+v"(v));
    return v;
}
__device__ __forceinline__ float plsw32(float v) {
    asm("v_permlane32_swap_b32 %0, %0" : "+v"(v));
    return v;
}

template <int MASK>
__device__ __forceinline__ float lxor(float v) {
    if constexpr (MASK == 1)
        return __int_as_float(__builtin_amdgcn_update_dpp(
            0, __float_as_int(v), 0xB1, 0xF, 0xF, true));       // quad_perm [1,0,3,2]
    else if constexpr (MASK == 2)
        return __int_as_float(__builtin_amdgcn_update_dpp(
            0, __float_as_int(v), 0x4E, 0xF, 0xF, true));       // quad_perm [2,3,0,1]
    else if constexpr (MASK == 4)
        return __int_as_float(__builtin_amdgcn_ds_swizzle(__float_as_int(v), 0x101F));
    else if constexpr (MASK == 8)
        return __int_as_float(__builtin_amdgcn_ds_swizzle(__float_as_int(v), 0x201F));
    else if constexpr (MASK == 16)
        return plsw16(v);
    else
        return plsw32(v);
}

template <int MASK>
__device__ __forceinline__ float2 lxor2(float2 v) {
    return make_float2(lxor<MASK>(v.x), lxor<MASK>(v.y));
}

template <int MASK>
__device__ __forceinline__ float rsum(float v) {
    return v + lxor<MASK>(v);
}

// load an M4 from wave-uniform global memory (compiler emits scalar loads)
__device__ __forceinline__ M4 ldm(const float* __restrict__ g) {
    M4 M;
    M.u00 = make_float2(g[0], g[1]); M.u01 = make_float2(g[2], g[3]);
    M.u10 = make_float2(g[4], g[5]); M.u11 = make_float2(g[6], g[7]);
    return M;
}

// ---------- register statevector, 2 samples per wave: amp[q][r], q=sample ----------
// idx bit b: b in [0,2] -> register bit b; b in [3,8] -> lane bit (b-3).
// wire w -> idx bit (8-w). Wires 0..5 = lane bits 5..0; wires 6,7,8 = reg bits 2,1,0.
// All gates loop q=0..1 inside the unrolled body -> two independent dep chains.

// single-qubit dense gate on register bit TB
template <int TB>
__device__ __forceinline__ void rot_reg(const M4& U, float2 (&amp)[2][8]) {
#pragma unroll
    for (int r = 0; r < 8; r++)
        if (((r >> TB) & 1) == 0) {
            int r1 = r | (1 << TB);
#pragma unroll
            for (int q = 0; q < 2; q++) {
                float2 a = amp[q][r], b = amp[q][r1];
                amp[q][r]  = cmac2(U.u00, a, U.u01, b);
                amp[q][r1] = cmac2(U.u10, a, U.u11, b);
            }
        }
}

// single-qubit dense gate on lane bit LB
template <int LB>
__device__ __forceinline__ void rot_lane(const M4& U, float2 (&amp)[2][8], int lane) {
    bool hi = (lane >> LB) & 1;
    float2 cA = hi ? U.u11 : U.u00;
    float2 cB = hi ? U.u10 : U.u01;
#pragma unroll
    for (int r = 0; r < 8; r++)
#pragma unroll
        for (int q = 0; q < 2; q++) {
            float2 o = lxor2<(1 << LB)>(amp[q][r]);
            amp[q][r] = cmac2(cA, amp[q][r], cB, o);
        }
}

template <int WIRE>
__device__ __forceinline__ void rot1(const M4& U, float2 (&amp)[2][8], int lane) {
    constexpr int BIT = 8 - WIRE;
    if constexpr (BIT < 3) rot_reg<BIT>(U, amp);
    else rot_lane<BIT - 3>(U, amp, lane);
}

// ---------- specialized controlled rotations (target = reg bit TB) ----------

// controlled RX: [[c, -i s], [-i s, c]]
template <int CBIT, int TB>
__device__ __forceinline__ void crx_g(float c, float s, float2 (&amp)[2][8], int lane) {
    if constexpr (CBIT >= 3) {
        bool ct = (lane >> (CBIT - 3)) & 1;
        float cc = ct ? c : 1.f, ss = ct ? s : 0.f;
#pragma unroll
        for (int r = 0; r < 8; r++)
            if (((r >> TB) & 1) == 0) {
                int r1 = r | (1 << TB);
#pragma unroll
                for (int q = 0; q < 2; q++) {
                    float2 a = amp[q][r], b = amp[q][r1];
                    amp[q][r]  = make_float2(cc * a.x + ss * b.y, cc * a.y - ss * b.x);
                    amp[q][r1] = make_float2(ss * a.y + cc * b.x, cc * b.y - ss * a.x);
                }
            }
    } else {
#pragma unroll
        for (int r = 0; r < 8; r++)
            if (((r >> CBIT) & 1) == 1 && ((r >> TB) & 1) == 0) {
                int r1 = r | (1 << TB);
#pragma unroll
                for (int q = 0; q < 2; q++) {
                    float2 a = amp[q][r], b = amp[q][r1];
                    amp[q][r]  = make_float2(c * a.x + s * b.y, c * a.y - s * b.x);
                    amp[q][r1] = make_float2(s * a.y + c * b.x, c * b.y - s * a.x);
                }
            }
    }
}

// controlled RY: [[c, -s], [s, c]] (real)
template <int CBIT, int TB>
__device__ __forceinline__ void cry_g(float c, float s, float2 (&amp)[2][8], int lane) {
    if constexpr (CBIT >= 3) {
        bool ct = (lane >> (CBIT - 3)) & 1;
        float cc = ct ? c : 1.f, ss = ct ? s : 0.f;
#pragma unroll
        for (int r = 0; r < 8; r++)
            if (((r >> TB) & 1) == 0) {
                int r1 = r | (1 << TB);
#pragma unroll
                for (int q = 0; q < 2; q++) {
                    float2 a = amp[q][r], b = amp[q][r1];
                    amp[q][r]  = make_float2(cc * a.x - ss * b.x, cc * a.y - ss * b.y);
                    amp[q][r1] = make_float2(ss * a.x + cc * b.x, ss * a.y + cc * b.y);
                }
            }
    } else {
#pragma unroll
        for (int r = 0; r < 8; r++)
            if (((r >> CBIT) & 1) == 1 && ((r >> TB) & 1) == 0) {
                int r1 = r | (1 << TB);
#pragma unroll
                for (int q = 0; q < 2; q++) {
                    float2 a = amp[q][r], b = amp[q][r1];
                    amp[q][r]  = make_float2(c * a.x - s * b.x, c * a.y - s * b.y);
                    amp[q][r1] = make_float2(s * a.x + c * b.x, s * a.y + c * b.y);
                }
            }
    }
}

// controlled RZ: diag(e, conj(e)), e = c - i s
template <int CBIT, int TB>
__device__ __forceinline__ void crz_g(float c, float s, float2 (&amp)[2][8], int lane) {
    if constexpr (CBIT >= 3) {
        bool ct = (lane >> (CBIT - 3)) & 1;
        float cc = ct ? c : 1.f, ss = ct ? s : 0.f;
#pragma unroll
        for (int r = 0; r < 8; r++)
            if (((r >> TB) & 1) == 0) {
                int r1 = r | (1 << TB);
#pragma unroll
                for (int q = 0; q < 2; q++) {
                    float2 a = amp[q][r], b = amp[q][r1];
                    amp[q][r]  = make_float2(cc * a.x + ss * a.y, cc * a.y - ss * a.x);
                    amp[q][r1] = make_float2(cc * b.x - ss * b.y, cc * b.y + ss * b.x);
                }
            }
    } else {
#pragma unroll
        for (int r = 0; r < 8; r++)
            if (((r >> CBIT) & 1) == 1 && ((r >> TB) & 1) == 0) {
                int r1 = r | (1 << TB);
#pragma unroll
                for (int q = 0; q < 2; q++) {
                    float2 a = amp[q][r], b = amp[q][r1];
                    amp[q][r]  = make_float2(c * a.x + s * a.y, c * a.y - s * a.x);
                    amp[q][r1] = make_float2(c * b.x - s * b.y, c * b.y + s * b.x);
                }
            }
    }
}

template <int CW, int TW>
__device__ __forceinline__ void cnotg(float2 (&amp)[2][8], int lane) {
    constexpr int CBIT = 8 - CW, TBIT = 8 - TW;
    if constexpr (CBIT < 3 && TBIT < 3) {
#pragma unroll
        for (int r = 0; r < 8; r++)
            if (((r >> CBIT) & 1) == 1 && ((r >> TBIT) & 1) == 0) {
                int r1 = r | (1 << TBIT);
#pragma unroll
                for (int q = 0; q < 2; q++) {
                    float2 t = amp[q][r]; amp[q][r] = amp[q][r1]; amp[q][r1] = t;
                }
            }
    } else if constexpr (CBIT >= 3 && TBIT < 3) {
        bool c = (lane >> (CBIT - 3)) & 1;
#pragma unroll
        for (int r = 0; r < 8; r++)
            if (((r >> TBIT) & 1) == 0) {
                int r1 = r | (1 << TBIT);
#pragma unroll
                for (int q = 0; q < 2; q++) {
                    float2 t0 = amp[q][r], t1 = amp[q][r1];
                    amp[q][r]  = c ? t1 : t0;
                    amp[q][r1] = c ? t0 : t1;
                }
            }
    } else if constexpr (CBIT < 3 && TBIT >= 3) {
#pragma unroll
        for (int r = 0; r < 8; r++)
            if (((r >> CBIT) & 1) == 1)
#pragma unroll
                for (int q = 0; q < 2; q++)
                    amp[q][r] = lxor2<(1 << (TBIT - 3))>(amp[q][r]);
    } else {
        bool c = (lane >> (CBIT - 3)) & 1;
#pragma unroll
        for (int r = 0; r < 8; r++)
#pragma unroll
            for (int q = 0; q < 2; q++) {
                float2 o = lxor2<(1 << (TBIT - 3))>(amp[q][r]);
                amp[q][r] = c ? o : amp[q][r];
            }
    }
}

// StronglyEntanglingLayers, L=1, 3 wires; gm = 3 precomputed dense Rot matrices
template <int W0, int W1, int W2>
__device__ __forceinline__ void sel3m(const float* __restrict__ gm, float2 (&amp)[2][8], int lane) {
    rot1<W0>(ldm(gm),      amp, lane);
    rot1<W1>(ldm(gm + 8),  amp, lane);
    rot1<W2>(ldm(gm + 16), amp, lane);
    cnotg<W0, W1>(amp, lane);
    cnotg<W1, W2>(amp, lane);
    cnotg<W2, W0>(amp, lane);
}

// gm layout (floats): [0..7] (c,s) x4 ctrl gates; [8..31] strong[0]; [32..55] strong[1]; [56..79] update
template <int I>
__device__ __forceinline__ void block_i(float2 (&amp)[2][8], float cx, float sx, float cy1, float sy1,
                                        float cz, float sz, float cy2, float sy2,
                                        const float* __restrict__ gm, int lane) {
    crx_g<4 - I, 1>(cx,  sx,  amp, lane);
    cry_g<8 - I, 1>(cy1, sy1, amp, lane);
    crz_g<4 - I, 0>(cz,  sz,  amp, lane);
    cry_g<8 - I, 0>(cy2, sy2, amp, lane);
    sel3m<I, 4 + I, 7>(gm + 8,  amp, lane);   // strong[0]
    sel3m<7, 4 + I, 8>(gm + 32, amp, lane);   // strong[1]
}

// ---------- kernel A': tiny prep (gate table + zero gsum/gcnt) ----------
__global__ void prep_kernel(const float* __restrict__ strong, const float* __restrict__ inits,
                            const float* __restrict__ update,
                            float* __restrict__ gm, float* __restrict__ zbuf, int nzero) {
    int j = threadIdx.x;
    if (j < 4) {
        gm[2 * j]     = cosf(0.5f * inits[j]);
        gm[2 * j + 1] = sinf(0.5f * inits[j]);
    } else if (j < 13) {
        const float* w;
        if (j < 7)       w = strong + (j - 4) * 3;
        else if (j < 10) w = strong + 9 + (j - 7) * 3;
        else             w = update + (j - 10) * 3;
        M4 M = mrot(w[0], w[1], w[2]);
        float* o = gm + 8 + (j - 4) * 8;
        o[0] = M.u00.x; o[1] = M.u00.y; o[2] = M.u01.x; o[3] = M.u01.y;
        o[4] = M.u10.x; o[5] = M.u10.y; o[6] = M.u11.x; o[7] = M.u11.y;
    }
    for (int i = j; i < nzero; i += 64) zbuf[i] = 0.f;
}

// ---------- kernel B: fused feature-MLPs + PQC + update-MLP + pooling ----------
// TWO samples per wave (amp[2][8]): every dependent gate chain gets an
// independent twin stream for ILP; wave-shared loads amortized 2x.
#define MAX_GRAPHS 64
__global__ __launch_bounds__(256) void pqc_fused_kernel(
        const float* __restrict__ node_feat, const float* __restrict__ edge_attr,
        const float* __restrict__ Wn1, const float* __restrict__ bn1,
        const float* __restrict__ Wn2, const float* __restrict__ bn2,
        const float* __restrict__ We1, const float* __restrict__ be1,
        const float* __restrict__ We2, const float* __restrict__ be2,
        const int* __restrict__ subgraphs, const int* __restrict__ edge_ids,
        const int* __restrict__ batch, const float* __restrict__ gm,
        const float* __restrict__ Wu1, const float* __restrict__ bu1,
        const float* __restrict__ Wu2, const float* __restrict__ bu2,
        float* __restrict__ gsum, float* __restrict__ gcnt,
        int ntot, int ngraphs) {
    __shared__ float bins[3 * MAX_GRAPHS];
    for (int i = threadIdx.x; i < 3 * ngraphs; i += 256) bins[i] = 0.f;
    __syncthreads();

    int wave = threadIdx.x >> 6;
    int lane = threadIdx.x & 63;
    int s0 = (blockIdx.x * 4 + wave) * 2;

    if (s0 < ntot) {
        int j1 = lane, j2 = lane + 64;
        bool ok1 = (s0 + 1) < ntot;
        int sq[2] = {s0, ok1 ? s0 + 1 : s0};

        // ---- per-lane weight preloads (L2-hot, shared by both samples) ----
        float wn1a[8], wn1b[8];
#pragma unroll
        for (int k = 0; k < 8; k++) { wn1a[k] = Wn1[k * 128 + j1]; wn1b[k] = Wn1[k * 128 + j2]; }
        float bn1a = bn1[j1], bn1b = bn1[j2];
        float wn2a0 = Wn2[2 * j1], wn2a1 = Wn2[2 * j1 + 1];
        float wn2b0 = Wn2[2 * j2], wn2b1 = Wn2[2 * j2 + 1];
        float we1a[4], we1b[4];
#pragma unroll
        for (int k = 0; k < 4; k++) { we1a[k] = We1[k * 128 + j1]; we1b[k] = We1[k * 128 + j2]; }
        float be1a = be1[j1], be1b = be1[j2];
        float we2a0 = We2[2 * j1], we2a1 = We2[2 * j1 + 1];
        float we2b0 = We2[2 * j2], we2b1 = We2[2 * j2 + 1];

        // ---- sample indices ----
        int cidx[2];
        int nid[2][4];
        int eid[2][3];
#pragma unroll
        for (int q = 0; q < 2; q++) {
            const int4 sg = *reinterpret_cast<const int4*>(subgraphs + (size_t)sq[q] * 4);
            cidx[q] = sg.x;
            nid[q][0] = sg.x; nid[q][1] = sg.y; nid[q][2] = sg.z; nid[q][3] = sg.w;
#pragma unroll
            for (int j = 0; j < 3; j++) eid[q][j] = edge_ids[sq[q] * 3 + j];
        }

        // ---- feature MLP partials: value idx 2r+ch, rows 0..2 edges, 3..6 nodes ----
        float o0a[2][7], o1a[2][7];
#pragma unroll
        for (int q = 0; q < 2; q++) {
#pragma unroll
            for (int j = 0; j < 3; j++) {
                const float4 f = *reinterpret_cast<const float4*>(edge_attr + (size_t)eid[q][j] * 4);
                float h1 = be1a + f.x * we1a[0] + f.y * we1a[1] + f.z * we1a[2] + f.w * we1a[3];
                float h2 = be1b + f.x * we1b[0] + f.y * we1b[1] + f.z * we1b[2] + f.w * we1b[3];
                h1 = h1 > 0.f ? h1 : 0.01f * h1;
                h2 = h2 > 0.f ? h2 : 0.01f * h2;
                o0a[q][j] = h1 * we2a0 + h2 * we2b0;
                o1a[q][j] = h1 * we2a1 + h2 * we2b1;
            }
#pragma unroll
            for (int j = 0; j < 4; j++) {
                const float4* nf = reinterpret_cast<const float4*>(node_feat + (size_t)nid[q][j] * 8);
                const float4 fa = nf[0], fb = nf[1];
                float h1 = bn1a + fa.x * wn1a[0] + fa.y * wn1a[1] + fa.z * wn1a[2] + fa.w * wn1a[3]
                                + fb.x * wn1a[4] + fb.y * wn1a[5] + fb.z * wn1a[6] + fb.w * wn1a[7];
                float h2 = bn1b + fa.x * wn1b[0] + fa.y * wn1b[1] + fa.z * wn1b[2] + fa.w * wn1b[3]
                                + fb.x * wn1b[4] + fb.y * wn1b[5] + fb.z * wn1b[6] + fb.w * wn1b[7];
                h1 = h1 > 0.f ? h1 : 0.01f * h1;
                h2 = h2 > 0.f ? h2 : 0.01f * h2;
                o0a[q][3 + j] = h1 * wn2a0 + h2 * wn2b0;
                o1a[q][3 + j] = h1 * wn2a1 + h2 * wn2b1;
            }
        }

        // ---- value-packing fold (both samples interleaved): lane j holds value j ----
        float L1[2][7];
#pragma unroll
        for (int i = 0; i < 7; i++)
#pragma unroll
            for (int q = 0; q < 2; q++) {
                float r0 = rsum<1>(o0a[q][i]);
                float r1 = rsum<1>(o1a[q][i]);
                L1[q][i] = (lane & 1) ? r1 : r0;
            }
        float L2[2][4];
#pragma unroll
        for (int i = 0; i < 3; i++)
#pragma unroll
            for (int q = 0; q < 2; q++) {
                float r0 = rsum<2>(L1[q][2 * i]);
                float r1 = rsum<2>(L1[q][2 * i + 1]);
                L2[q][i] = (lane & 2) ? r1 : r0;
            }
#pragma unroll
        for (int q = 0; q < 2; q++) L2[q][3] = rsum<2>(L1[q][6]);
        float L3[2][2];
#pragma unroll
        for (int i = 0; i < 2; i++)
#pragma unroll
            for (int q = 0; q < 2; q++) {
                float r0 = rsum<4>(L2[q][2 * i]);
                float r1 = rsum<4>(L2[q][2 * i + 1]);
                L3[q][i] = (lane & 4) ? r1 : r0;
            }
        float T[2];
#pragma unroll
        for (int q = 0; q < 2; q++) {
            float r0 = rsum<8>(L3[q][0]);
            float r1 = rsum<8>(L3[q][1]);
            T[q] = (lane & 8) ? r1 : r0;
            T[q] = rsum<16>(T[q]);
            T[q] = rsum<32>(T[q]);
        }

        // ---- tanh + half-angle trig on designated lanes (0..13) ----
        float be2_0 = be2[0], be2_1 = be2[1];
        float bn2_0 = bn2[0], bn2_1 = bn2[1];
        float bias = (lane < 6) ? ((lane & 1) ? be2_1 : be2_0)
                                : ((lane & 1) ? bn2_1 : bn2_0);
        float t[2], ca[2], sa[2];
#pragma unroll
        for (int q = 0; q < 2; q++) {
            t[q]  = fast_tanh(T[q] + bias) * PI_F;   // valid on lanes 0..13
            float ah = 0.5f * t[q];
            ca[q] = __cosf(ah);
            sa[q] = __sinf(ah);
        }
        float f0[2], f1[2];
#pragma unroll
        for (int q = 0; q < 2; q++) {
            f0[q] = __shfl(t[q], 6, 64);   // ang[3][0] = x[cidx].0
            f1[q] = __shfl(t[q], 7, 64);   // ang[3][1] = x[cidx].1
        }

        // ---- encoding layer on |0..0>: product state; broadcast fused per wire ----
        float2 cacc[2] = {make_float2(1.f, 0.f), make_float2(1.f, 0.f)};
#pragma unroll
        for (int w = 0; w < 6; w++) {
            int bit = (lane >> (5 - w)) & 1;
#pragma unroll
            for (int q = 0; q < 2; q++) {
                float c0 = __shfl(ca[q], 2 * w, 64);
                float s0 = __shfl(sa[q], 2 * w, 64);
                float c1 = __shfl(ca[q], 2 * w + 1, 64);
                float s1 = __shfl(sa[q], 2 * w + 1, 64);
                float2 v0 = make_float2(c0 * c1, -c0 * s1);
                float2 v1 = make_float2(s0 * c1,  s0 * s1);
                cacc[q] = cmul2(cacc[q], bit ? v1 : v0);
            }
        }
        float2 amp[2][8];
#pragma unroll
        for (int q = 0; q < 2; q++) {
#pragma unroll
            for (int r = 0; r < 8; r++) amp[q][r] = make_float2(0.f, 0.f);
            float c6 = __shfl(ca[q], 12, 64);
            float s6 = __shfl(sa[q], 12, 64);
            float c7 = __shfl(ca[q], 13, 64);
            float s7 = __shfl(sa[q], 13, 64);
            amp[q][0] = cmul2(cacc[q], make_float2(c6 * c7, -c6 * s7));
            amp[q][4] = cmul2(cacc[q], make_float2(s6 * c7,  s6 * s7));
        }

        // ---- PQC (both samples interleaved inside every gate) ----
        float cx  = gm[0], sx  = gm[1];
        float cy1 = gm[2], sy1 = gm[3];
        float cz  = gm[4], sz  = gm[5];
        float cy2 = gm[6], sy2 = gm[7];

        block_i<0>(amp, cx, sx, cy1, sy1, cz, sz, cy2, sy2, gm, lane);
        block_i<1>(amp, cx, sx, cy1, sy1, cz, sz, cy2, sy2, gm, lane);
        block_i<2>(amp, cx, sx, cy1, sy1, cz, sz, cy2, sy2, gm, lane);
        sel3m<3, 7, 8>(gm + 56, amp, lane);

        // <X_3>: pair product (mask 4) then butterfly
        float acc[2] = {0.f, 0.f};
#pragma unroll
        for (int r = 0; r < 8; r++)
#pragma unroll
            for (int q = 0; q < 2; q++) {
                float2 o = lxor2<4>(amp[q][r]);
                acc[q] += amp[q][r].x * o.x + amp[q][r].y * o.y;
            }
#pragma unroll
        for (int q = 0; q < 2; q++) {
            acc[q] = rsum<1>(acc[q]);
            acc[q] = rsum<2>(acc[q]);
            acc[q] = rsum<4>(acc[q]);
            acc[q] = rsum<8>(acc[q]);
            acc[q] = rsum<16>(acc[q]);
            acc[q] = rsum<32>(acc[q]);
        }

        // ---- update MLP [f0,f1,acc] -> 128 -> 2, wave-parallel, both samples ----
        float wu1a0 = Wu1[j1], wu1a1 = Wu1[128 + j1], wu1a2 = Wu1[256 + j1], bu1a = bu1[j1];
        float wu1b0 = Wu1[j2], wu1b1 = Wu1[128 + j2], wu1b2 = Wu1[256 + j2], bu1b = bu1[j2];
        float wu2a0 = Wu2[2 * j1], wu2a1 = Wu2[2 * j1 + 1];
        float wu2b0 = Wu2[2 * j2], wu2b1 = Wu2[2 * j2 + 1];
        float o0[2], o1[2];
#pragma unroll
        for (int q = 0; q < 2; q++) {
            float h1 = bu1a + f0[q] * wu1a0 + f1[q] * wu1a1 + acc[q] * wu1a2;
            float h2 = bu1b + f0[q] * wu1b0 + f1[q] * wu1b1 + acc[q] * wu1b2;
            h1 = h1 > 0.f ? h1 : 0.01f * h1;
            h2 = h2 > 0.f ? h2 : 0.01f * h2;
            o0[q] = h1 * wu2a0 + h2 * wu2b0;
            o1[q] = h1 * wu2a1 + h2 * wu2b1;
        }
#pragma unroll
        for (int q = 0; q < 2; q++) {
            o0[q] = rsum<1>(o0[q]);  o1[q] = rsum<1>(o1[q]);
            o0[q] = rsum<2>(o0[q]);  o1[q] = rsum<2>(o1[q]);
            o0[q] = rsum<4>(o0[q]);  o1[q] = rsum<4>(o1[q]);
            o0[q] = rsum<8>(o0[q]);  o1[q] = rsum<8>(o1[q]);
            o0[q] = rsum<16>(o0[q]); o1[q] = rsum<16>(o1[q]);
            o0[q] = rsum<32>(o0[q]); o1[q] = rsum<32>(o1[q]);
        }

        // ---- pooling: x[s] (pre-update) + scattered update ----
        float xs0[2], xs1[2];
#pragma unroll
        for (int q = 0; q < 2; q++) { xs0[q] = f0[q]; xs1[q] = f1[q]; }
#pragma unroll
        for (int q = 0; q < 2; q++)
            if (cidx[q] != sq[q]) {
                // generic fallback (cold; never taken for this input layout)
                const float4* nf = reinterpret_cast<const float4*>(node_feat + (size_t)sq[q] * 8);
                const float4 fa = nf[0], fb = nf[1];
                float g1 = bn1a, g2 = bn1b;
                const float fv[8] = {fa.x, fa.y, fa.z, fa.w, fb.x, fb.y, fb.z, fb.w};
#pragma unroll
                for (int k = 0; k < 8; k++) {
                    g1 += fv[k] * wn1a[k];
                    g2 += fv[k] * wn1b[k];
                }
                g1 = g1 > 0.f ? g1 : 0.01f * g1;
                g2 = g2 > 0.f ? g2 : 0.01f * g2;
                float p0 = g1 * wn2a0 + g2 * wn2b0;
                float p1 = g1 * wn2a1 + g2 * wn2b1;
                for (int off = 32; off > 0; off >>= 1) {
                    p0 += __shfl_xor(p0, off, 64);
                    p1 += __shfl_xor(p1, off, 64);
                }
                xs0[q] = tanhf(p0 + bn2_0) * PI_F;
                xs1[q] = tanhf(p1 + bn2_1) * PI_F;
            }

        if (lane == 0) {
#pragma unroll
            for (int q = 0; q < 2; q++) {
                if (q == 1 && !ok1) break;
                float u0 = o0[q] + bu2[0], u1 = o1[q] + bu2[1];
                int bs = batch[sq[q]], bc = batch[cidx[q]];
                atomicAdd(&bins[3 * bs + 0], xs0[q]);
                atomicAdd(&bins[3 * bs + 1], xs1[q]);
                atomicAdd(&bins[3 * bs + 2], 1.f);
                atomicAdd(&bins[3 * bc + 0], u0);
                atomicAdd(&bins[3 * bc + 1], u1);
            }
        }
    }
    __syncthreads();

    // flush non-zero bins (typically 1 graph per block)
    for (int i = threadIdx.x; i < ngraphs; i += 256) {
        float a0 = bins[3 * i + 0], a1 = bins[3 * i + 1], ac = bins[3 * i + 2];
        if (a0 != 0.f || a1 != 0.f || ac != 0.f) {
            atomicAdd(&gsum[2 * i + 0], a0);
            atomicAdd(&gsum[2 * i + 1], a1);
            atomicAdd(&gcnt[i], ac);
        }
    }
}

// ---------- kernel C: g = gsum/gcnt; out = mlp(g, 2->2->2) ----------
__global__ void head_kernel(const float* __restrict__ gsum, const float* __restrict__ gcnt,
                            const float* __restrict__ Wh1, const float* __restrict__ bh1,
                            const float* __restrict__ Wh2, const float* __restrict__ bh2,
                            float* __restrict__ out, int ngraphs) {
    int g = threadIdx.x;
    if (g >= ngraphs) return;
    float c = gcnt[g];
    float g0 = gsum[2 * g + 0] / c;
    float g1 = gsum[2 * g + 1] / c;
    float h0 = g0 * Wh1[0] + g1 * Wh1[2] + bh1[0];
    float h1 = g0 * Wh1[1] + g1 * Wh1[3] + bh1[1];
    h0 = h0 > 0.f ? h0 : 0.01f * h0;
    h1 = h1 > 0.f ? h1 : 0.01f * h1;
    out[2 * g + 0] = h0 * Wh2[0] + h1 * Wh2[2] + bh2[0];
    out[2 * g + 1] = h0 * Wh2[1] + h1 * Wh2[3] + bh2[1];
}

extern "C" void kernel_launch(void* const* d_in, const int* in_sizes, int n_in,
                              void* d_out, int out_size, void* d_ws, size_t ws_size,
                              hipStream_t stream) {
    const float* node_feat = (const float*)d_in[0];   // (N, 8)
    const float* edge_attr = (const float*)d_in[1];   // (3N, 4)
    const float* Wn1 = (const float*)d_in[2];
    const float* bn1 = (const float*)d_in[3];
    const float* Wn2 = (const float*)d_in[4];
    const float* bn2 = (const float*)d_in[5];
    const float* We1 = (const float*)d_in[6];
    const float* be1 = (const float*)d_in[7];
    const float* We2 = (const float*)d_in[8];
    const float* be2 = (const float*)d_in[9];
    const float* strong = (const float*)d_in[10];     // (2,1,3,3)
    const float* inits  = (const float*)d_in[11];     // (1,4)
    const float* update = (const float*)d_in[12];     // (1,3,3)
    const float* Wu1 = (const float*)d_in[13];
    const float* bu1 = (const float*)d_in[14];
    const float* Wu2 = (const float*)d_in[15];
    const float* bu2 = (const float*)d_in[16];
    const float* Wh1 = (const float*)d_in[17];
    const float* bh1 = (const float*)d_in[18];
    const float* Wh2 = (const float*)d_in[19];
    const float* bh2 = (const float*)d_in[20];
    const int* subgraphs = (const int*)d_in[21];      // (N, 4)
    const int* edge_ids  = (const int*)d_in[22];      // (N, 3)
    const int* batch     = (const int*)d_in[23];      // (N,)

    const int N  = in_sizes[0] / 8;      // 4096 nodes (= samples)
    const int NG = out_size / 2;         // 16 graphs

    // workspace layout (floats)
    float* ws   = (float*)d_ws;
    float* gsum = ws;                    // NG*2
    float* gcnt = gsum + (size_t)NG * 2; // NG       (contiguous with gsum)
    float* gm   = gcnt + NG;             // 80 floats of gate data

    // Kernel A': gate table + zero gsum/gcnt (1 block)
    prep_kernel<<<1, 64, 0, stream>>>(strong, inits, update, gm, gsum, 3 * NG);

    // Kernel B: fused feature-MLPs + PQC + update MLP + pooling (2 samples/wave)
    pqc_fused_kernel<<<(N + 7) / 8, 256, 0, stream>>>(
        node_feat, edge_attr, Wn1, bn1, Wn2, bn2, We1, be1, We2, be2,
        subgraphs, edge_ids, batch, gm, Wu1, bu1, Wu2, bu2,
        gsum, gcnt, N, NG);

    // Kernel C: head
    head_kernel<<<1, 64, 0, stream>>>(gsum, gcnt, Wh1, bh1, Wh2, bh2, (float*)d_out, NG);
}

// Round 5
// 130.991 us; speedup vs baseline: 1.1604x; 1.0296x over previous
//
#include <hip/hip_runtime.h>
#include <math.h>

#define PI_F 3.14159265358979323846f

// ---------- complex helpers (float2 as complex) ----------
__device__ __forceinline__ float2 cmul2(float2 a, float2 b) {
    return make_float2(a.x * b.x - a.y * b.y, a.x * b.y + a.y * b.x);
}
// u*a + v*b
__device__ __forceinline__ float2 cmac2(float2 u, float2 a, float2 v, float2 b) {
    float2 r;
    r.x = u.x * a.x - u.y * a.y + v.x * b.x - v.y * b.y;
    r.y = u.x * a.y + u.y * a.x + v.x * b.y + v.y * b.x;
    return r;
}

struct M4 { float2 u00, u01, u10, u11; };

__device__ __forceinline__ M4 mmul4(const M4& A, const M4& B) {
    M4 R;
    R.u00 = cmac2(A.u00, B.u00, A.u01, B.u10);
    R.u01 = cmac2(A.u00, B.u01, A.u01, B.u11);
    R.u10 = cmac2(A.u10, B.u00, A.u11, B.u10);
    R.u11 = cmac2(A.u10, B.u01, A.u11, B.u11);
    return R;
}
__device__ __forceinline__ M4 mry(float t) {
    float c = cosf(0.5f * t), s = sinf(0.5f * t);
    M4 R; R.u00 = {c, 0}; R.u01 = {-s, 0}; R.u10 = {s, 0}; R.u11 = {c, 0};
    return R;
}
__device__ __forceinline__ M4 mrz(float t) {
    float c = cosf(0.5f * t), s = sinf(0.5f * t);
    M4 R; R.u00 = {c, -s}; R.u01 = {0, 0}; R.u10 = {0, 0}; R.u11 = {c, s};
    return R;
}
// Rot(phi, theta, omega) = RZ(omega) @ RY(theta) @ RZ(phi)
__device__ __forceinline__ M4 mrot(float phi, float th, float om) {
    return mmul4(mmul4(mrz(om), mry(th)), mrz(phi));
}

// fast tanh on the trans pipe: 1 - 2/(e^{2x}+1); exact to ~1e-6, saturates
// correctly at +-1 for |x| large.
__device__ __forceinline__ float fast_tanh(float x) {
    float e = __expf(2.f * x);
    return 1.f - 2.f / (e + 1.f);
}

// ---------- cross-lane xor-exchange (verified R3) ----------
// mask 1,2  -> DPP quad_perm (VALU)
// mask 4,8  -> ds_swizzle (DS pipe)
// mask 16,32-> v_permlane16/32_swap, both operands the same register (VALU)
__device__ __forceinline__ float plsw16(float v) {
    asm("v_permlane16_swap_b32 %0, %0" : "+v"(v));
    return v;
}
__device__ __forceinline__ float plsw32(float v) {
    asm("v_permlane32_swap_b32 %0, %0" : "+v"(v));
    return v;
}

template <int MASK>
__device__ __forceinline__ float lxor(float v) {
    if constexpr (MASK == 1)
        return __int_as_float(__builtin_amdgcn_update_dpp(
            0, __float_as_int(v), 0xB1, 0xF, 0xF, true));       // quad_perm [1,0,3,2]
    else if constexpr (MASK == 2)
        return __int_as_float(__builtin_amdgcn_update_dpp(
            0, __float_as_int(v), 0x4E, 0xF, 0xF, true));       // quad_perm [2,3,0,1]
    else if constexpr (MASK == 4)
        return __int_as_float(__builtin_amdgcn_ds_swizzle(__float_as_int(v), 0x101F));
    else if constexpr (MASK == 8)
        return __int_as_float(__builtin_amdgcn_ds_swizzle(__float_as_int(v), 0x201F));
    else if constexpr (MASK == 16)
        return plsw16(v);
    else
        return plsw32(v);
}

template <int MASK>
__device__ __forceinline__ float2 lxor2(float2 v) {
    return make_float2(lxor<MASK>(v.x), lxor<MASK>(v.y));
}

template <int MASK>
__device__ __forceinline__ float rsum(float v) {
    return v + lxor<MASK>(v);
}

// load an M4 from wave-uniform global memory (compiler emits scalar loads)
__device__ __forceinline__ M4 ldm(const float* __restrict__ g) {
    M4 M;
    M.u00 = make_float2(g[0], g[1]); M.u01 = make_float2(g[2], g[3]);
    M.u10 = make_float2(g[4], g[5]); M.u11 = make_float2(g[6], g[7]);
    return M;
}

// ---------- register statevector, 2 samples per wave: amp[q][r], q=sample ----------
// idx bit b: b in [0,2] -> register bit b; b in [3,8] -> lane bit (b-3).
// wire w -> idx bit (8-w). Wires 0..5 = lane bits 5..0; wires 6,7,8 = reg bits 2,1,0.

// single-qubit dense gate on register bit TB
template <int TB>
__device__ __forceinline__ void rot_reg(const M4& U, float2 (&amp)[2][8]) {
#pragma unroll
    for (int r = 0; r < 8; r++)
        if (((r >> TB) & 1) == 0) {
            int r1 = r | (1 << TB);
#pragma unroll
            for (int q = 0; q < 2; q++) {
                float2 a = amp[q][r], b = amp[q][r1];
                amp[q][r]  = cmac2(U.u00, a, U.u01, b);
                amp[q][r1] = cmac2(U.u10, a, U.u11, b);
            }
        }
}

// single-qubit dense gate on lane bit LB
template <int LB>
__device__ __forceinline__ void rot_lane(const M4& U, float2 (&amp)[2][8], int lane) {
    bool hi = (lane >> LB) & 1;
    float2 cA = hi ? U.u11 : U.u00;
    float2 cB = hi ? U.u10 : U.u01;
#pragma unroll
    for (int r = 0; r < 8; r++)
#pragma unroll
        for (int q = 0; q < 2; q++) {
            float2 o = lxor2<(1 << LB)>(amp[q][r]);
            amp[q][r] = cmac2(cA, amp[q][r], cB, o);
        }
}

template <int WIRE>
__device__ __forceinline__ void rot1(const M4& U, float2 (&amp)[2][8], int lane) {
    constexpr int BIT = 8 - WIRE;
    if constexpr (BIT < 3) rot_reg<BIT>(U, amp);
    else rot_lane<BIT - 3>(U, amp, lane);
}

// ---------- specialized controlled rotations (target = reg bit TB) ----------

// controlled RX: [[c, -i s], [-i s, c]]
template <int CBIT, int TB>
__device__ __forceinline__ void crx_g(float c, float s, float2 (&amp)[2][8], int lane) {
    if constexpr (CBIT >= 3) {
        bool ct = (lane >> (CBIT - 3)) & 1;
        float cc = ct ? c : 1.f, ss = ct ? s : 0.f;
#pragma unroll
        for (int r = 0; r < 8; r++)
            if (((r >> TB) & 1) == 0) {
                int r1 = r | (1 << TB);
#pragma unroll
                for (int q = 0; q < 2; q++) {
                    float2 a = amp[q][r], b = amp[q][r1];
                    amp[q][r]  = make_float2(cc * a.x + ss * b.y, cc * a.y - ss * b.x);
                    amp[q][r1] = make_float2(ss * a.y + cc * b.x, cc * b.y - ss * a.x);
                }
            }
    } else {
#pragma unroll
        for (int r = 0; r < 8; r++)
            if (((r >> CBIT) & 1) == 1 && ((r >> TB) & 1) == 0) {
                int r1 = r | (1 << TB);
#pragma unroll
                for (int q = 0; q < 2; q++) {
                    float2 a = amp[q][r], b = amp[q][r1];
                    amp[q][r]  = make_float2(c * a.x + s * b.y, c * a.y - s * b.x);
                    amp[q][r1] = make_float2(s * a.y + c * b.x, c * b.y - s * a.x);
                }
            }
    }
}

// controlled RY: [[c, -s], [s, c]] (real)
template <int CBIT, int TB>
__device__ __forceinline__ void cry_g(float c, float s, float2 (&amp)[2][8], int lane) {
    if constexpr (CBIT >= 3) {
        bool ct = (lane >> (CBIT - 3)) & 1;
        float cc = ct ? c : 1.f, ss = ct ? s : 0.f;
#pragma unroll
        for (int r = 0; r < 8; r++)
            if (((r >> TB) & 1) == 0) {
                int r1 = r | (1 << TB);
#pragma unroll
                for (int q = 0; q < 2; q++) {
                    float2 a = amp[q][r], b = amp[q][r1];
                    amp[q][r]  = make_float2(cc * a.x - ss * b.x, cc * a.y - ss * b.y);
                    amp[q][r1] = make_float2(ss * a.x + cc * b.x, ss * a.y + cc * b.y);
                }
            }
    } else {
#pragma unroll
        for (int r = 0; r < 8; r++)
            if (((r >> CBIT) & 1) == 1 && ((r >> TB) & 1) == 0) {
                int r1 = r | (1 << TB);
#pragma unroll
                for (int q = 0; q < 2; q++) {
                    float2 a = amp[q][r], b = amp[q][r1];
                    amp[q][r]  = make_float2(c * a.x - s * b.x, c * a.y - s * b.y);
                    amp[q][r1] = make_float2(s * a.x + c * b.x, s * a.y + c * b.y);
                }
            }
    }
}

// controlled RZ: diag(e, conj(e)), e = c - i s
template <int CBIT, int TB>
__device__ __forceinline__ void crz_g(float c, float s, float2 (&amp)[2][8], int lane) {
    if constexpr (CBIT >= 3) {
        bool ct = (lane >> (CBIT - 3)) & 1;
        float cc = ct ? c : 1.f, ss = ct ? s : 0.f;
#pragma unroll
        for (int r = 0; r < 8; r++)
            if (((r >> TB) & 1) == 0) {
                int r1 = r | (1 << TB);
#pragma unroll
                for (int q = 0; q < 2; q++) {
                    float2 a = amp[q][r], b = amp[q][r1];
                    amp[q][r]  = make_float2(cc * a.x + ss * a.y, cc * a.y - ss * a.x);
                    amp[q][r1] = make_float2(cc * b.x - ss * b.y, cc * b.y + ss * b.x);
                }
            }
    } else {
#pragma unroll
        for (int r = 0; r < 8; r++)
            if (((r >> CBIT) & 1) == 1 && ((r >> TB) & 1) == 0) {
                int r1 = r | (1 << TB);
#pragma unroll
                for (int q = 0; q < 2; q++) {
                    float2 a = amp[q][r], b = amp[q][r1];
                    amp[q][r]  = make_float2(c * a.x + s * a.y, c * a.y - s * a.x);
                    amp[q][r1] = make_float2(c * b.x - s * b.y, c * b.y + s * b.x);
                }
            }
    }
}

template <int CW, int TW>
__device__ __forceinline__ void cnotg(float2 (&amp)[2][8], int lane) {
    constexpr int CBIT = 8 - CW, TBIT = 8 - TW;
    if constexpr (CBIT < 3 && TBIT < 3) {
#pragma unroll
        for (int r = 0; r < 8; r++)
            if (((r >> CBIT) & 1) == 1 && ((r >> TBIT) & 1) == 0) {
                int r1 = r | (1 << TBIT);
#pragma unroll
                for (int q = 0; q < 2; q++) {
                    float2 t = amp[q][r]; amp[q][r] = amp[q][r1]; amp[q][r1] = t;
                }
            }
    } else if constexpr (CBIT >= 3 && TBIT < 3) {
        bool c = (lane >> (CBIT - 3)) & 1;
#pragma unroll
        for (int r = 0; r < 8; r++)
            if (((r >> TBIT) & 1) == 0) {
                int r1 = r | (1 << TBIT);
#pragma unroll
                for (int q = 0; q < 2; q++) {
                    float2 t0 = amp[q][r], t1 = amp[q][r1];
                    amp[q][r]  = c ? t1 : t0;
                    amp[q][r1] = c ? t0 : t1;
                }
            }
    } else if constexpr (CBIT < 3 && TBIT >= 3) {
#pragma unroll
        for (int r = 0; r < 8; r++)
            if (((r >> CBIT) & 1) == 1)
#pragma unroll
                for (int q = 0; q < 2; q++)
                    amp[q][r] = lxor2<(1 << (TBIT - 3))>(amp[q][r]);
    } else {
        bool c = (lane >> (CBIT - 3)) & 1;
#pragma unroll
        for (int r = 0; r < 8; r++)
#pragma unroll
            for (int q = 0; q < 2; q++) {
                float2 o = lxor2<(1 << (TBIT - 3))>(amp[q][r]);
                amp[q][r] = c ? o : amp[q][r];
            }
    }
}

// StronglyEntanglingLayers, L=1, 3 wires; matrices hoisted to registers by caller
template <int W0, int W1, int W2>
__device__ __forceinline__ void sel3m(const M4& A, const M4& B, const M4& C,
                                      float2 (&amp)[2][8], int lane) {
    rot1<W0>(A, amp, lane);
    rot1<W1>(B, amp, lane);
    rot1<W2>(C, amp, lane);
    cnotg<W0, W1>(amp, lane);
    cnotg<W1, W2>(amp, lane);
    cnotg<W2, W0>(amp, lane);
}

template <int I>
__device__ __forceinline__ void block_i(float2 (&amp)[2][8], float cx, float sx, float cy1, float sy1,
                                        float cz, float sz, float cy2, float sy2,
                                        const M4& S0a, const M4& S0b, const M4& S0c,
                                        const M4& S1a, const M4& S1b, const M4& S1c, int lane) {
    crx_g<4 - I, 1>(cx,  sx,  amp, lane);
    cry_g<8 - I, 1>(cy1, sy1, amp, lane);
    crz_g<4 - I, 0>(cz,  sz,  amp, lane);
    cry_g<8 - I, 0>(cy2, sy2, amp, lane);
    sel3m<I, 4 + I, 7>(S0a, S0b, S0c, amp, lane);   // strong[0]
    sel3m<7, 4 + I, 8>(S1a, S1b, S1c, amp, lane);   // strong[1]
}

// ---------- kernel A': tiny prep (gate table + zero gsum/gcnt) ----------
__global__ void prep_kernel(const float* __restrict__ strong, const float* __restrict__ inits,
                            const float* __restrict__ update,
                            float* __restrict__ gm, float* __restrict__ zbuf, int nzero) {
    int j = threadIdx.x;
    if (j < 4) {
        gm[2 * j]     = cosf(0.5f * inits[j]);
        gm[2 * j + 1] = sinf(0.5f * inits[j]);
    } else if (j < 13) {
        const float* w;
        if (j < 7)       w = strong + (j - 4) * 3;
        else if (j < 10) w = strong + 9 + (j - 7) * 3;
        else             w = update + (j - 10) * 3;
        M4 M = mrot(w[0], w[1], w[2]);
        float* o = gm + 8 + (j - 4) * 8;
        o[0] = M.u00.x; o[1] = M.u00.y; o[2] = M.u01.x; o[3] = M.u01.y;
        o[4] = M.u10.x; o[5] = M.u10.y; o[6] = M.u11.x; o[7] = M.u11.y;
    }
    for (int i = j; i < nzero; i += 64) zbuf[i] = 0.f;
}

// ---------- kernel B: fused feature-MLPs + PQC + update-MLP + pooling ----------
// TWO samples per wave; gate table fully hoisted to registers at kernel start
// (launch_bounds min-waves=2 matches the grid-limited occupancy, giving the
// allocator ~256 VGPRs so the 64 uniform gate floats stay live).
#define MAX_GRAPHS 64
__global__ __launch_bounds__(256, 2) void pqc_fused_kernel(
        const float* __restrict__ node_feat, const float* __restrict__ edge_attr,
        const float* __restrict__ Wn1, const float* __restrict__ bn1,
        const float* __restrict__ Wn2, const float* __restrict__ bn2,
        const float* __restrict__ We1, const float* __restrict__ be1,
        const float* __restrict__ We2, const float* __restrict__ be2,
        const int* __restrict__ subgraphs, const int* __restrict__ edge_ids,
        const int* __restrict__ batch, const float* __restrict__ gm,
        const float* __restrict__ Wu1, const float* __restrict__ bu1,
        const float* __restrict__ Wu2, const float* __restrict__ bu2,
        float* __restrict__ gsum, float* __restrict__ gcnt,
        int ntot, int ngraphs) {
    __shared__ float bins[3 * MAX_GRAPHS];
    for (int i = threadIdx.x; i < 3 * ngraphs; i += 256) bins[i] = 0.f;
    __syncthreads();

    int wave = threadIdx.x >> 6;
    int lane = threadIdx.x & 63;
    int s0 = (blockIdx.x * 4 + wave) * 2;

    if (s0 < ntot) {
        int j1 = lane, j2 = lane + 64;
        bool ok1 = (s0 + 1) < ntot;
        int sq[2] = {s0, ok1 ? s0 + 1 : s0};

        // ---- gate table: hoist ALL uniform loads to the top; latency hides
        //      under the feature-MLP phase and values stay live through the PQC.
        float cx  = gm[0], sx  = gm[1];
        float cy1 = gm[2], sy1 = gm[3];
        float cz  = gm[4], sz  = gm[5];
        float cy2 = gm[6], sy2 = gm[7];
        M4 S0a = ldm(gm + 8),  S0b = ldm(gm + 16), S0c = ldm(gm + 24);
        M4 S1a = ldm(gm + 32), S1b = ldm(gm + 40), S1c = ldm(gm + 48);
        M4 Upa = ldm(gm + 56), Upb = ldm(gm + 64), Upc = ldm(gm + 72);

        // ---- per-lane weight preloads (L2-hot, shared by both samples) ----
        float wn1a[8], wn1b[8];
#pragma unroll
        for (int k = 0; k < 8; k++) { wn1a[k] = Wn1[k * 128 + j1]; wn1b[k] = Wn1[k * 128 + j2]; }
        float bn1a = bn1[j1], bn1b = bn1[j2];
        float wn2a0 = Wn2[2 * j1], wn2a1 = Wn2[2 * j1 + 1];
        float wn2b0 = Wn2[2 * j2], wn2b1 = Wn2[2 * j2 + 1];
        float we1a[4], we1b[4];
#pragma unroll
        for (int k = 0; k < 4; k++) { we1a[k] = We1[k * 128 + j1]; we1b[k] = We1[k * 128 + j2]; }
        float be1a = be1[j1], be1b = be1[j2];
        float we2a0 = We2[2 * j1], we2a1 = We2[2 * j1 + 1];
        float we2b0 = We2[2 * j2], we2b1 = We2[2 * j2 + 1];

        // ---- sample indices ----
        int cidx[2];
        int nid[2][4];
        int eid[2][3];
#pragma unroll
        for (int q = 0; q < 2; q++) {
            const int4 sg = *reinterpret_cast<const int4*>(subgraphs + (size_t)sq[q] * 4);
            cidx[q] = sg.x;
            nid[q][0] = sg.x; nid[q][1] = sg.y; nid[q][2] = sg.z; nid[q][3] = sg.w;
#pragma unroll
            for (int j = 0; j < 3; j++) eid[q][j] = edge_ids[sq[q] * 3 + j];
        }

        // ---- feature MLP partials: value idx 2r+ch, rows 0..2 edges, 3..6 nodes ----
        float o0a[2][7], o1a[2][7];
#pragma unroll
        for (int q = 0; q < 2; q++) {
#pragma unroll
            for (int j = 0; j < 3; j++) {
                const float4 f = *reinterpret_cast<const float4*>(edge_attr + (size_t)eid[q][j] * 4);
                float h1 = be1a + f.x * we1a[0] + f.y * we1a[1] + f.z * we1a[2] + f.w * we1a[3];
                float h2 = be1b + f.x * we1b[0] + f.y * we1b[1] + f.z * we1b[2] + f.w * we1b[3];
                h1 = h1 > 0.f ? h1 : 0.01f * h1;
                h2 = h2 > 0.f ? h2 : 0.01f * h2;
                o0a[q][j] = h1 * we2a0 + h2 * we2b0;
                o1a[q][j] = h1 * we2a1 + h2 * we2b1;
            }
#pragma unroll
            for (int j = 0; j < 4; j++) {
                const float4* nf = reinterpret_cast<const float4*>(node_feat + (size_t)nid[q][j] * 8);
                const float4 fa = nf[0], fb = nf[1];
                float h1 = bn1a + fa.x * wn1a[0] + fa.y * wn1a[1] + fa.z * wn1a[2] + fa.w * wn1a[3]
                                + fb.x * wn1a[4] + fb.y * wn1a[5] + fb.z * wn1a[6] + fb.w * wn1a[7];
                float h2 = bn1b + fa.x * wn1b[0] + fa.y * wn1b[1] + fa.z * wn1b[2] + fa.w * wn1b[3]
                                + fb.x * wn1b[4] + fb.y * wn1b[5] + fb.z * wn1b[6] + fb.w * wn1b[7];
                h1 = h1 > 0.f ? h1 : 0.01f * h1;
                h2 = h2 > 0.f ? h2 : 0.01f * h2;
                o0a[q][3 + j] = h1 * wn2a0 + h2 * wn2b0;
                o1a[q][3 + j] = h1 * wn2a1 + h2 * wn2b1;
            }
        }

        // ---- value-packing fold (both samples interleaved): lane j holds value j ----
        float L1[2][7];
#pragma unroll
        for (int i = 0; i < 7; i++)
#pragma unroll
            for (int q = 0; q < 2; q++) {
                float r0 = rsum<1>(o0a[q][i]);
                float r1 = rsum<1>(o1a[q][i]);
                L1[q][i] = (lane & 1) ? r1 : r0;
            }
        float L2[2][4];
#pragma unroll
        for (int i = 0; i < 3; i++)
#pragma unroll
            for (int q = 0; q < 2; q++) {
                float r0 = rsum<2>(L1[q][2 * i]);
                float r1 = rsum<2>(L1[q][2 * i + 1]);
                L2[q][i] = (lane & 2) ? r1 : r0;
            }
#pragma unroll
        for (int q = 0; q < 2; q++) L2[q][3] = rsum<2>(L1[q][6]);
        float L3[2][2];
#pragma unroll
        for (int i = 0; i < 2; i++)
#pragma unroll
            for (int q = 0; q < 2; q++) {
                float r0 = rsum<4>(L2[q][2 * i]);
                float r1 = rsum<4>(L2[q][2 * i + 1]);
                L3[q][i] = (lane & 4) ? r1 : r0;
            }
        float T[2];
#pragma unroll
        for (int q = 0; q < 2; q++) {
            float r0 = rsum<8>(L3[q][0]);
            float r1 = rsum<8>(L3[q][1]);
            T[q] = (lane & 8) ? r1 : r0;
            T[q] = rsum<16>(T[q]);
            T[q] = rsum<32>(T[q]);
        }

        // ---- tanh + half-angle trig on designated lanes (0..13) ----
        float be2_0 = be2[0], be2_1 = be2[1];
        float bn2_0 = bn2[0], bn2_1 = bn2[1];
        float bias = (lane < 6) ? ((lane & 1) ? be2_1 : be2_0)
                                : ((lane & 1) ? bn2_1 : bn2_0);
        float t[2], ca[2], sa[2];
#pragma unroll
        for (int q = 0; q < 2; q++) {
            t[q]  = fast_tanh(T[q] + bias) * PI_F;   // valid on lanes 0..13
            float ah = 0.5f * t[q];
            ca[q] = __cosf(ah);
            sa[q] = __sinf(ah);
        }
        float f0[2], f1[2];
#pragma unroll
        for (int q = 0; q < 2; q++) {
            f0[q] = __shfl(t[q], 6, 64);   // ang[3][0] = x[cidx].0
            f1[q] = __shfl(t[q], 7, 64);   // ang[3][1] = x[cidx].1
        }

        // ---- encoding layer on |0..0>: product state; broadcast fused per wire ----
        float2 cacc[2] = {make_float2(1.f, 0.f), make_float2(1.f, 0.f)};
#pragma unroll
        for (int w = 0; w < 6; w++) {
            int bit = (lane >> (5 - w)) & 1;
#pragma unroll
            for (int q = 0; q < 2; q++) {
                float c0 = __shfl(ca[q], 2 * w, 64);
                float s0 = __shfl(sa[q], 2 * w, 64);
                float c1 = __shfl(ca[q], 2 * w + 1, 64);
                float s1 = __shfl(sa[q], 2 * w + 1, 64);
                float2 v0 = make_float2(c0 * c1, -c0 * s1);
                float2 v1 = make_float2(s0 * c1,  s0 * s1);
                cacc[q] = cmul2(cacc[q], bit ? v1 : v0);
            }
        }
        float2 amp[2][8];
#pragma unroll
        for (int q = 0; q < 2; q++) {
#pragma unroll
            for (int r = 0; r < 8; r++) amp[q][r] = make_float2(0.f, 0.f);
            float c6 = __shfl(ca[q], 12, 64);
            float s6 = __shfl(sa[q], 12, 64);
            float c7 = __shfl(ca[q], 13, 64);
            float s7 = __shfl(sa[q], 13, 64);
            amp[q][0] = cmul2(cacc[q], make_float2(c6 * c7, -c6 * s7));
            amp[q][4] = cmul2(cacc[q], make_float2(s6 * c7,  s6 * s7));
        }

        // ---- PQC (both samples interleaved inside every gate) ----
        block_i<0>(amp, cx, sx, cy1, sy1, cz, sz, cy2, sy2, S0a, S0b, S0c, S1a, S1b, S1c, lane);
        block_i<1>(amp, cx, sx, cy1, sy1, cz, sz, cy2, sy2, S0a, S0b, S0c, S1a, S1b, S1c, lane);
        block_i<2>(amp, cx, sx, cy1, sy1, cz, sz, cy2, sy2, S0a, S0b, S0c, S1a, S1b, S1c, lane);
        sel3m<3, 7, 8>(Upa, Upb, Upc, amp, lane);

        // <X_3>: pair product (mask 4) then butterfly
        float acc[2] = {0.f, 0.f};
#pragma unroll
        for (int r = 0; r < 8; r++)
#pragma unroll
            for (int q = 0; q < 2; q++) {
                float2 o = lxor2<4>(amp[q][r]);
                acc[q] += amp[q][r].x * o.x + amp[q][r].y * o.y;
            }
#pragma unroll
        for (int q = 0; q < 2; q++) {
            acc[q] = rsum<1>(acc[q]);
            acc[q] = rsum<2>(acc[q]);
            acc[q] = rsum<4>(acc[q]);
            acc[q] = rsum<8>(acc[q]);
            acc[q] = rsum<16>(acc[q]);
            acc[q] = rsum<32>(acc[q]);
        }

        // ---- update MLP [f0,f1,acc] -> 128 -> 2, wave-parallel, both samples ----
        float wu1a0 = Wu1[j1], wu1a1 = Wu1[128 + j1], wu1a2 = Wu1[256 + j1], bu1a = bu1[j1];
        float wu1b0 = Wu1[j2], wu1b1 = Wu1[128 + j2], wu1b2 = Wu1[256 + j2], bu1b = bu1[j2];
        float wu2a0 = Wu2[2 * j1], wu2a1 = Wu2[2 * j1 + 1];
        float wu2b0 = Wu2[2 * j2], wu2b1 = Wu2[2 * j2 + 1];
        float o0[2], o1[2];
#pragma unroll
        for (int q = 0; q < 2; q++) {
            float h1 = bu1a + f0[q] * wu1a0 + f1[q] * wu1a1 + acc[q] * wu1a2;
            float h2 = bu1b + f0[q] * wu1b0 + f1[q] * wu1b1 + acc[q] * wu1b2;
            h1 = h1 > 0.f ? h1 : 0.01f * h1;
            h2 = h2 > 0.f ? h2 : 0.01f * h2;
            o0[q] = h1 * wu2a0 + h2 * wu2b0;
            o1[q] = h1 * wu2a1 + h2 * wu2b1;
        }
#pragma unroll
        for (int q = 0; q < 2; q++) {
            o0[q] = rsum<1>(o0[q]);  o1[q] = rsum<1>(o1[q]);
            o0[q] = rsum<2>(o0[q]);  o1[q] = rsum<2>(o1[q]);
            o0[q] = rsum<4>(o0[q]);  o1[q] = rsum<4>(o1[q]);
            o0[q] = rsum<8>(o0[q]);  o1[q] = rsum<8>(o1[q]);
            o0[q] = rsum<16>(o0[q]); o1[q] = rsum<16>(o1[q]);
            o0[q] = rsum<32>(o0[q]); o1[q] = rsum<32>(o1[q]);
        }

        // ---- pooling: x[s] (pre-update) + scattered update ----
        float xs0[2], xs1[2];
#pragma unroll
        for (int q = 0; q < 2; q++) { xs0[q] = f0[q]; xs1[q] = f1[q]; }
#pragma unroll
        for (int q = 0; q < 2; q++)
            if (cidx[q] != sq[q]) {
                // generic fallback (cold; never taken for this input layout)
                const float4* nf = reinterpret_cast<const float4*>(node_feat + (size_t)sq[q] * 8);
                const float4 fa = nf[0], fb = nf[1];
                float g1 = bn1a, g2 = bn1b;
                const float fv[8] = {fa.x, fa.y, fa.z, fa.w, fb.x, fb.y, fb.z, fb.w};
#pragma unroll
                for (int k = 0; k < 8; k++) {
                    g1 += fv[k] * wn1a[k];
                    g2 += fv[k] * wn1b[k];
                }
                g1 = g1 > 0.f ? g1 : 0.01f * g1;
                g2 = g2 > 0.f ? g2 : 0.01f * g2;
                float p0 = g1 * wn2a0 + g2 * wn2b0;
                float p1 = g1 * wn2a1 + g2 * wn2b1;
                for (int off = 32; off > 0; off >>= 1) {
                    p0 += __shfl_xor(p0, off, 64);
                    p1 += __shfl_xor(p1, off, 64);
                }
                xs0[q] = tanhf(p0 + bn2_0) * PI_F;
                xs1[q] = tanhf(p1 + bn2_1) * PI_F;
            }

        if (lane == 0) {
#pragma unroll
            for (int q = 0; q < 2; q++) {
                if (q == 1 && !ok1) break;
                float u0 = o0[q] + bu2[0], u1 = o1[q] + bu2[1];
                int bs = batch[sq[q]], bc = batch[cidx[q]];
                atomicAdd(&bins[3 * bs + 0], xs0[q]);
                atomicAdd(&bins[3 * bs + 1], xs1[q]);
                atomicAdd(&bins[3 * bs + 2], 1.f);
                atomicAdd(&bins[3 * bc + 0], u0);
                atomicAdd(&bins[3 * bc + 1], u1);
            }
        }
    }
    __syncthreads();

    // flush non-zero bins (typically 1 graph per block)
    for (int i = threadIdx.x; i < ngraphs; i += 256) {
        float a0 = bins[3 * i + 0], a1 = bins[3 * i + 1], ac = bins[3 * i + 2];
        if (a0 != 0.f || a1 != 0.f || ac != 0.f) {
            atomicAdd(&gsum[2 * i + 0], a0);
            atomicAdd(&gsum[2 * i + 1], a1);
            atomicAdd(&gcnt[i], ac);
        }
    }
}

// ---------- kernel C: g = gsum/gcnt; out = mlp(g, 2->2->2) ----------
__global__ void head_kernel(const float* __restrict__ gsum, const float* __restrict__ gcnt,
                            const float* __restrict__ Wh1, const float* __restrict__ bh1,
                            const float* __restrict__ Wh2, const float* __restrict__ bh2,
                            float* __restrict__ out, int ngraphs) {
    int g = threadIdx.x;
    if (g >= ngraphs) return;
    float c = gcnt[g];
    float g0 = gsum[2 * g + 0] / c;
    float g1 = gsum[2 * g + 1] / c;
    float h0 = g0 * Wh1[0] + g1 * Wh1[2] + bh1[0];
    float h1 = g0 * Wh1[1] + g1 * Wh1[3] + bh1[1];
    h0 = h0 > 0.f ? h0 : 0.01f * h0;
    h1 = h1 > 0.f ? h1 : 0.01f * h1;
    out[2 * g + 0] = h0 * Wh2[0] + h1 * Wh2[2] + bh2[0];
    out[2 * g + 1] = h0 * Wh2[1] + h1 * Wh2[3] + bh2[1];
}

extern "C" void kernel_launch(void* const* d_in, const int* in_sizes, int n_in,
                              void* d_out, int out_size, void* d_ws, size_t ws_size,
                              hipStream_t stream) {
    const float* node_feat = (const float*)d_in[0];   // (N, 8)
    const float* edge_attr = (const float*)d_in[1];   // (3N, 4)
    const float* Wn1 = (const float*)d_in[2];
    const float* bn1 = (const float*)d_in[3];
    const float* Wn2 = (const float*)d_in[4];
    const float* bn2 = (const float*)d_in[5];
    const float* We1 = (const float*)d_in[6];
    const float* be1 = (const float*)d_in[7];
    const float* We2 = (const float*)d_in[8];
    const float* be2 = (const float*)d_in[9];
    const float* strong = (const float*)d_in[10];     // (2,1,3,3)
    const float* inits  = (const float*)d_in[11];     // (1,4)
    const float* update = (const float*)d_in[12];     // (1,3,3)
    const float* Wu1 = (const float*)d_in[13];
    const float* bu1 = (const float*)d_in[14];
    const float* Wu2 = (const float*)d_in[15];
    const float* bu2 = (const float*)d_in[16];
    const float* Wh1 = (const float*)d_in[17];
    const float* bh1 = (const float*)d_in[18];
    const float* Wh2 = (const float*)d_in[19];
    const float* bh2 = (const float*)d_in[20];
    const int* subgraphs = (const int*)d_in[21];      // (N, 4)
    const int* edge_ids  = (const int*)d_in[22];      // (N, 3)
    const int* batch     = (const int*)d_in[23];      // (N,)

    const int N  = in_sizes[0] / 8;      // 4096 nodes (= samples)
    const int NG = out_size / 2;         // 16 graphs

    // workspace layout (floats)
    float* ws   = (float*)d_ws;
    float* gsum = ws;                    // NG*2
    float* gcnt = gsum + (size_t)NG * 2; // NG       (contiguous with gsum)
    float* gm   = gcnt + NG;             // 80 floats of gate data

    // Kernel A': gate table + zero gsum/gcnt (1 block)
    prep_kernel<<<1, 64, 0, stream>>>(strong, inits, update, gm, gsum, 3 * NG);

    // Kernel B: fused feature-MLPs + PQC + update MLP + pooling (2 samples/wave)
    pqc_fused_kernel<<<(N + 7) / 8, 256, 0, stream>>>(
        node_feat, edge_attr, Wn1, bn1, Wn2, bn2, We1, be1, We2, be2,
        subgraphs, edge_ids, batch, gm, Wu1, bu1, Wu2, bu2,
        gsum, gcnt, N, NG);

    // Kernel C: head
    head_kernel<<<1, 64, 0, stream>>>(gsum, gcnt, Wh1, bh1, Wh2, bh2, (float*)d_out, NG);
}